// Round 9
// baseline (400.919 us; speedup 1.0000x reference)
//
#include <hip/hip_runtime.h>
#include <hip/hip_fp16.h>

#define CBW  1024
#define CBSH 10
#define CCAP 20480
#define SRCM 0x1FFFF

typedef _Float16 f16x8 __attribute__((ext_vector_type(8)));
typedef float f32x4 __attribute__((ext_vector_type(4)));

__device__ __forceinline__ float lrelu(float v) { return v >= 0.0f ? v : 0.01f * v; }
// decode packed edge weight: top 15 bits = positive bf16 (sans sign)
__device__ __forceinline__ float decw(unsigned p) { return __uint_as_float((p >> 17) << 16); }

// ============ pass 1: histogram-partition counting sort (u32 payload) ============
__global__ __launch_bounds__(256) void k_part(const int* __restrict__ row,
                                              const int* __restrict__ col,
                                              int* __restrict__ bcur,
                                              unsigned* __restrict__ bedges, int E, int NB) {
  __shared__ int hist[128];
  __shared__ int gbase[128];
  const int t = threadIdx.x;
  const int base = blockIdx.x * 2048 + t * 8;
  int r[8], c[8];
  if (base + 8 <= E) {
    int4 r0 = *(const int4*)&row[base], r1 = *(const int4*)&row[base + 4];
    int4 c0 = *(const int4*)&col[base], c1 = *(const int4*)&col[base + 4];
    r[0] = r0.x; r[1] = r0.y; r[2] = r0.z; r[3] = r0.w;
    r[4] = r1.x; r[5] = r1.y; r[6] = r1.z; r[7] = r1.w;
    c[0] = c0.x; c[1] = c0.y; c[2] = c0.z; c[3] = c0.w;
    c[4] = c1.x; c[5] = c1.y; c[6] = c1.z; c[7] = c1.w;
  } else {
#pragma unroll
    for (int j = 0; j < 8; ++j) {
      bool ok = (base + j) < E;
      r[j] = ok ? row[base + j] : 0;
      c[j] = ok ? col[base + j] : -1;
    }
  }
  if (t < 128) hist[t] = 0;
  __syncthreads();
#pragma unroll
  for (int j = 0; j < 8; ++j)
    if (c[j] >= 0) atomicAdd(&hist[c[j] >> CBSH], 1);
  __syncthreads();
  if (t < NB && hist[t] > 0) gbase[t] = atomicAdd(&bcur[t * 16], hist[t]);
  __syncthreads();
  if (t < 128) hist[t] = 0;  // reuse as local cursor
  __syncthreads();
#pragma unroll
  for (int j = 0; j < 8; ++j) {
    if (c[j] < 0) continue;
    int b = c[j] >> CBSH;
    int lp = atomicAdd(&hist[b], 1);
    int p = gbase[b] + lp;
    if (p < CCAP)
      bedges[(size_t)b * CCAP + p] = ((unsigned)(c[j] & (CBW - 1)) << 17) | (unsigned)r[j];
  }
}

// ============ scan bucket counts ============
__global__ void k_scanb(const int* __restrict__ bcur, int* __restrict__ bstart, int NB) {
  __shared__ int lds[1024];
  int t = threadIdx.x;
  int v = (t < NB) ? min(bcur[t * 16], CCAP) : 0;
  lds[t] = v;
  __syncthreads();
  for (int off = 1; off < 1024; off <<= 1) {
    int x = (t >= off) ? lds[t - off] : 0;
    __syncthreads();
    lds[t] += x;
    __syncthreads();
  }
  if (t < NB) bstart[t] = (t > 0) ? lds[t - 1] : 0;
}

// ============ pass 2: per-bucket LDS histogram -> rowstart, dinv ============
__global__ __launch_bounds__(256) void k_rows(const int* __restrict__ bcur,
                                              const int* __restrict__ bstart,
                                              const unsigned* __restrict__ bedges,
                                              int* __restrict__ rowstart,
                                              float* __restrict__ dinv, int N) {
  __shared__ int hist[CBW];
  __shared__ int tsum[256];
  int b = blockIdx.x, t = threadIdx.x;
  int cnt = min(bcur[b * 16], CCAP);
  int gbs = bstart[b];
  for (int i = t; i < CBW; i += 256) hist[i] = 0;
  __syncthreads();
  const unsigned* be = bedges + (size_t)b * CCAP;
  for (int i = t; i < cnt; i += 256) atomicAdd(&hist[be[i] >> 17], 1);
  __syncthreads();
  int h0 = hist[t * 4], h1 = hist[t * 4 + 1], h2 = hist[t * 4 + 2], h3 = hist[t * 4 + 3];
  int s0 = h0, s1 = s0 + h1, s2 = s1 + h2, s3 = s2 + h3;
  tsum[t] = s3;
  __syncthreads();
  for (int off = 1; off < 256; off <<= 1) {
    int x = (t >= off) ? tsum[t - off] : 0;
    __syncthreads();
    tsum[t] += x;
    __syncthreads();
  }
  int prefix = (t > 0) ? tsum[t - 1] : 0;
  int node0 = (b << CBSH) + t * 4;
  int ends[4] = {s0, s1, s2, s3};
  int hs[4] = {h0, h1, h2, h3};
#pragma unroll
  for (int j = 0; j < 4; ++j) {
    int node = node0 + j;
    if (node < N) {
      rowstart[node + 1] = gbs + prefix + ends[j];
      dinv[node] = rsqrtf((float)hs[j] + 1.0f);
    }
  }
  if (b == 0 && t == 0) rowstart[0] = 0;
}

// ============ pass 3: per-bucket CSR fill, packed u32 {w:15, src:17} ============
__global__ __launch_bounds__(256) void k_fill2(const int* __restrict__ bcur,
                                               const int* __restrict__ bstart,
                                               const unsigned* __restrict__ bedges,
                                               const int* __restrict__ rowstart,
                                               const float* __restrict__ dinv,
                                               unsigned* __restrict__ csr, int N) {
  __shared__ int cur[CBW];
  __shared__ float dv[CBW];
  int b = blockIdx.x, t = threadIdx.x;
  int cnt = min(bcur[b * 16], CCAP);
  for (int i = t; i < CBW; i += 256) {
    int node = (b << CBSH) + i;
    cur[i] = (node < N) ? rowstart[node] : 0;
    dv[i] = (node < N) ? dinv[node] : 0.0f;
  }
  __syncthreads();
  const unsigned* be = bedges + (size_t)b * CCAP;
  for (int i = t; i < cnt; i += 256) {
    unsigned pe = be[i];
    int src = pe & SRCM;
    int lc = pe >> 17;
    int pos = atomicAdd(&cur[lc], 1);
    float w = dinv[src] * dv[lc];
    unsigned wb = (__float_as_uint(w) + 0x8000u) >> 16;  // bf16 round-to-nearest, sign=0
    csr[pos] = (wb << 17) | (unsigned)src;
  }
}

// ============ W fp32 -> fp16 MFMA B-fragment packs (both weights, one dispatch) ============
__device__ __forceinline__ void cvtW_one(const float* W, __half* Wf, int idx) {
  int i = idx & 7, l = (idx >> 3) & 63, cb = (idx >> 9) & 7, kc = idx >> 12;
  int ks = kc * 32 + ((l >> 4) << 3) + i;
  int c = cb * 16 + (l & 15);
  Wf[idx] = __float2half(W[ks * 128 + c]);
}
__global__ __launch_bounds__(256) void k_cvtWs(const float* __restrict__ W1,
                                               const float* __restrict__ W2,
                                               __half* __restrict__ Wf1,
                                               __half* __restrict__ Wf2) {
  int idx = blockIdx.x * 256 + threadIdx.x;
  if (idx < 64 * 128) cvtW_one(W1, Wf1, idx);
  else if (idx < 192 * 128) cvtW_one(W2, Wf2, idx - 64 * 128);
}

// ============ x fp32 -> fp16 ============
__global__ __launch_bounds__(256) void k_cvt_x(const float* __restrict__ X,
                                               __half* __restrict__ Xh, size_t total4) {
  size_t i = (size_t)(blockIdx.x * 256 + threadIdx.x);
  if (i >= total4) return;
  float4 v = *(const float4*)&X[i * 4];
  __half2* dst = (__half2*)&Xh[i * 4];
  dst[0] = __floats2half2_rn(v.x, v.y);
  dst[1] = __floats2half2_rn(v.z, v.w);
}

// ============ layer 1 fused: agg64(xh) -> LDS tile -> MFMA -> h1h ============
// 4 waves/block; wave owns 16 nodes end-to-end. Per-wave LDS 16x64 fp16, XOR-swizzled.
__global__ __launch_bounds__(256) void k_l1(const int* __restrict__ rowstart,
                                            const unsigned* __restrict__ csr,
                                            const float* __restrict__ dinv,
                                            const __half* __restrict__ Xh,
                                            const __half* __restrict__ Wf1,
                                            const float* __restrict__ bias,
                                            __half* __restrict__ Y, int N) {
  __shared__ __align__(16) unsigned char As[4 * 2048];
  const int t = threadIdx.x;
  const int lane = t & 63;
  const int wv = t >> 6;
  const int nodebase = blockIdx.x * 64 + wv * 16;
  unsigned char* wb = As + wv * 2048;
  // phase A: aggregate 16 nodes, lane = feature
  for (int j = 0; j < 16; ++j) {
    int node = nodebase + j;
    unsigned addr = (unsigned)(j * 128) + (((unsigned)(lane * 2)) ^ ((unsigned)(j & 7) << 4));
    float acc = 0.0f;
    if (node < N) {
      int s = rowstart[node], e = rowstart[node + 1];
      float dc = dinv[node];
      acc = __half2float(Xh[(size_t)node * 64 + lane]) * dc * dc;  // self loop
#pragma unroll 4
      for (int i = s; i < e; ++i) {
        unsigned p = csr[i];
        acc += __half2float(Xh[(size_t)(p & SRCM) * 64 + lane]) * decw(p);
      }
    }
    *(__half*)(wb + addr) = __float2half(acc);
  }
  // phase B: MFMA 16x128, K=64
  const int lr = lane & 15, lg = lane >> 4;
  f32x4 acc8[8];
#pragma unroll
  for (int cb = 0; cb < 8; ++cb) acc8[cb] = (f32x4){0.f, 0.f, 0.f, 0.f};
  const _Float16* Wp = (const _Float16*)Wf1 + (size_t)lane * 8;
#pragma unroll
  for (int kc = 0; kc < 2; ++kc) {
    f16x8 a = *(const f16x8*)(wb + lr * 128 +
                              (((unsigned)(kc * 64 + lg * 16)) ^ ((unsigned)(lr & 7) << 4)));
#pragma unroll
    for (int cb = 0; cb < 8; ++cb) {
      f16x8 b = *(const f16x8*)(Wp + (size_t)((kc * 8 + cb) * 64) * 8);
      acc8[cb] = __builtin_amdgcn_mfma_f32_16x16x32_f16(a, b, acc8[cb], 0, 0, 0);
    }
  }
#pragma unroll
  for (int cb = 0; cb < 8; ++cb) {
    int c = cb * 16 + lr;
    float bv = bias[c];
#pragma unroll
    for (int v = 0; v < 4; ++v) {
      int gr = nodebase + lg * 4 + v;
      if (gr < N) Y[(size_t)gr * 128 + c] = __float2half(lrelu(acc8[cb][v] + bv));
    }
  }
}

// ============ layer 2 fused: agg128(h1h) -> LDS tile -> MFMA -> h2h ============
__global__ __launch_bounds__(256) void k_l2(const int* __restrict__ rowstart,
                                            const unsigned* __restrict__ csr,
                                            const float* __restrict__ dinv,
                                            const __half* __restrict__ H,
                                            const __half* __restrict__ Wf2,
                                            const float* __restrict__ bias,
                                            __half* __restrict__ Y, int N) {
  __shared__ __align__(16) unsigned char As[4 * 4096];
  const int t = threadIdx.x;
  const int lane = t & 63;
  const int wv = t >> 6;
  const int nodebase = blockIdx.x * 64 + wv * 16;
  unsigned char* wb = As + wv * 4096;
  const __half2* Hv = (const __half2*)H;
  // phase A: aggregate 16 nodes, lane = feature pair
  for (int j = 0; j < 16; ++j) {
    int node = nodebase + j;
    unsigned addr = (unsigned)(j * 256) + (((unsigned)(lane * 4)) ^ ((unsigned)(j & 7) << 4));
    float2 acc = make_float2(0.f, 0.f);
    if (node < N) {
      int s = rowstart[node], e = rowstart[node + 1];
      float dc = dinv[node];
      float2 hs = __half22float2(Hv[(size_t)node * 64 + lane]);
      acc.x = hs.x * dc * dc;
      acc.y = hs.y * dc * dc;
#pragma unroll 4
      for (int i = s; i < e; ++i) {
        unsigned p = csr[i];
        float w = decw(p);
        float2 h = __half22float2(Hv[(size_t)(p & SRCM) * 64 + lane]);
        acc.x += h.x * w;
        acc.y += h.y * w;
      }
    }
    *(__half2*)(wb + addr) = __floats2half2_rn(acc.x, acc.y);
  }
  // phase B: MFMA 16x128, K=128
  const int lr = lane & 15, lg = lane >> 4;
  f32x4 acc8[8];
#pragma unroll
  for (int cb = 0; cb < 8; ++cb) acc8[cb] = (f32x4){0.f, 0.f, 0.f, 0.f};
  const _Float16* Wp = (const _Float16*)Wf2 + (size_t)lane * 8;
#pragma unroll
  for (int kc = 0; kc < 4; ++kc) {
    f16x8 a = *(const f16x8*)(wb + lr * 256 +
                              (((unsigned)(kc * 64 + lg * 16)) ^ ((unsigned)(lr & 7) << 4)));
#pragma unroll
    for (int cb = 0; cb < 8; ++cb) {
      f16x8 b = *(const f16x8*)(Wp + (size_t)((kc * 8 + cb) * 64) * 8);
      acc8[cb] = __builtin_amdgcn_mfma_f32_16x16x32_f16(a, b, acc8[cb], 0, 0, 0);
    }
  }
#pragma unroll
  for (int cb = 0; cb < 8; ++cb) {
    int c = cb * 16 + lr;
    float bv = bias[c];
#pragma unroll
    for (int v = 0; v < 4; ++v) {
      int gr = nodebase + lg * 4 + v;
      if (gr < N) Y[(size_t)gr * 128 + c] = __float2half(lrelu(acc8[cb][v] + bv));
    }
  }
}

// ============ head: pool (binary search boundaries) + MLP, one block per graph ============
__global__ __launch_bounds__(256) void k_head(const __half* __restrict__ H,
                                              const int* __restrict__ batch, int N,
                                              const float* __restrict__ gfeat,
                                              const float* __restrict__ Wg, const float* __restrict__ bg,
                                              const float* __restrict__ Wf, const float* __restrict__ bf,
                                              const float* __restrict__ Wm1, const float* __restrict__ bm1,
                                              const float* __restrict__ Wm2, const float* __restrict__ bm2,
                                              float* __restrict__ out) {
  __shared__ float2 lds[256];
  __shared__ float p[128], a[256], qf[32], red[2];
  __shared__ int se[2];
  int g = blockIdx.x, t = threadIdx.x;
  if (t < 2) {  // lower_bound(batch, g + t)
    int target = g + t;
    int lo = 0, hi = N;
    while (lo < hi) {
      int mid = (lo + hi) >> 1;
      if (batch[mid] < target) lo = mid + 1; else hi = mid;
    }
    se[t] = lo;
  }
  if (t >= 2 && t < 34) qf[t - 2] = gfeat[(size_t)g * 32 + (t - 2)];
  __syncthreads();
  int s = se[0], e = se[1];
  int c2 = t & 63, q = t >> 6;
  const __half2* Hv = (const __half2*)H;
  float2 acc = make_float2(0.f, 0.f);
  for (int i = s + q; i < e; i += 4) {
    float2 h = __half22float2(Hv[(size_t)i * 64 + c2]);
    acc.x += h.x;
    acc.y += h.y;
  }
  lds[t] = acc;
  __syncthreads();
  if (t < 64) {
    float2 x0 = lds[t], x1 = lds[t + 64], x2 = lds[t + 128], x3 = lds[t + 192];
    float inv = 1.0f / fmaxf((float)(e - s), 1.0f);
    p[t * 2]     = (x0.x + x1.x + x2.x + x3.x) * inv;
    p[t * 2 + 1] = (x0.y + x1.y + x2.y + x3.y) * inv;
  }
  __syncthreads();
  if (t < 128) {
    float z1 = bg[t];
    for (int m = 0; m < 128; ++m) z1 += p[m] * Wg[m * 128 + t];
    float z2 = bf[t];
    for (int m = 0; m < 32; ++m) z2 += qf[m] * Wf[m * 128 + t];
    a[t] = lrelu(z1);
    a[128 + t] = lrelu(z2);
  }
  __syncthreads();
  if (t < 128) {
    float z = bm1[t];
    for (int k = 0; k < 256; ++k) z += a[k] * Wm1[k * 128 + t];
    z = lrelu(z);
    float v = z * Wm2[t];
#pragma unroll
    for (int off = 32; off; off >>= 1) v += __shfl_down(v, off);
    if ((t & 63) == 0) red[t >> 6] = v;
  }
  __syncthreads();
  if (t == 0) out[g] = red[0] + red[1] + bm2[0];
}

extern "C" void kernel_launch(void* const* d_in, const int* in_sizes, int n_in,
                              void* d_out, int out_size, void* d_ws, size_t ws_size,
                              hipStream_t stream) {
  const float* x     = (const float*)d_in[0];
  const int*   ei    = (const int*)d_in[1];
  const int*   batch = (const int*)d_in[2];
  const float* gfeat = (const float*)d_in[3];
  const float* W1 = (const float*)d_in[4];
  const float* b1 = (const float*)d_in[5];
  const float* W2 = (const float*)d_in[6];
  const float* b2 = (const float*)d_in[7];
  const float* Wg = (const float*)d_in[8];
  const float* bg = (const float*)d_in[9];
  const float* Wf = (const float*)d_in[10];
  const float* bf = (const float*)d_in[11];
  const float* Wm1 = (const float*)d_in[12];
  const float* bm1 = (const float*)d_in[13];
  const float* Wm2 = (const float*)d_in[14];
  const float* bm2 = (const float*)d_in[15];
  float* out = (float*)d_out;

  const int N = in_sizes[0] / 64;
  const int E = in_sizes[1] / 2;
  const int G = in_sizes[3] / 32;
  const int* row = ei;
  const int* col = ei + E;
  const int NB = (N + CBW - 1) >> CBSH;

  // ---- workspace (no aliasing; ~79 MB) ----
  char* w = (char*)d_ws;
  size_t off = 0;
  auto alloc = [&](size_t bytes) {
    void* p = w + off;
    off = (off + bytes + 255) & ~(size_t)255;
    return p;
  };
  int*      bcur     = (int*)alloc((size_t)NB * 16 * 4);
  int*      bstart   = (int*)alloc((size_t)NB * 4);
  int*      rowstart = (int*)alloc((size_t)(N + 1) * 4);
  float*    dinv     = (float*)alloc((size_t)N * 4);
  __half*   Wf1      = (__half*)alloc((size_t)64 * 128 * 2);
  __half*   Wf2      = (__half*)alloc((size_t)128 * 128 * 2);
  unsigned* bedges   = (unsigned*)alloc((size_t)NB * CCAP * 4);
  unsigned* csr      = (unsigned*)alloc((size_t)E * 4);
  __half*   xh       = (__half*)alloc((size_t)N * 64 * 2);
  __half*   h1h      = (__half*)alloc((size_t)N * 128 * 2);
  __half*   h2h      = (__half*)alloc((size_t)N * 128 * 2);
  (void)ws_size;

  hipMemsetAsync(bcur, 0, (size_t)NB * 16 * 4, stream);

  // CSR build
  k_part<<<(E + 2047) / 2048, 256, 0, stream>>>(row, col, bcur, bedges, E, NB);
  k_scanb<<<1, 1024, 0, stream>>>(bcur, bstart, NB);
  k_rows<<<NB, 256, 0, stream>>>(bcur, bstart, bedges, rowstart, dinv, N);
  k_fill2<<<NB, 256, 0, stream>>>(bcur, bstart, bedges, rowstart, dinv, csr, N);

  // weight packs + x->fp16
  k_cvtWs<<<(192 * 128 + 255) / 256, 256, 0, stream>>>(W1, W2, Wf1, Wf2);
  const size_t total4 = (size_t)N * 16;
  k_cvt_x<<<(int)((total4 + 255) / 256), 256, 0, stream>>>(x, xh, total4);

  const int gemmGrid = (N + 63) / 64;

  // fused layers
  k_l1<<<gemmGrid, 256, 0, stream>>>(rowstart, csr, dinv, xh, Wf1, b1, h1h, N);
  k_l2<<<gemmGrid, 256, 0, stream>>>(rowstart, csr, dinv, h1h, Wf2, b2, h2h, N);

  // pool + MLP head
  k_head<<<G, 256, 0, stream>>>(h2h, batch, N, gfeat, Wg, bg, Wf, bf, Wm1, bm1, Wm2, bm2, out);
}

// Round 10
// 303.455 us; speedup vs baseline: 1.3212x; 1.3212x over previous
//
#include <hip/hip_runtime.h>
#include <hip/hip_fp16.h>

#define CBW  1024
#define CBSH 10
#define CCAP 20480
#define SRCM 0x1FFFF

typedef _Float16 f16x8 __attribute__((ext_vector_type(8)));
typedef float f32x4 __attribute__((ext_vector_type(4)));

__device__ __forceinline__ float lrelu(float v) { return v >= 0.0f ? v : 0.01f * v; }
// decode packed edge weight: top 15 bits = positive bf16 (sans sign)
__device__ __forceinline__ float decw(unsigned p) { return __uint_as_float((p >> 17) << 16); }

// ============ pass 1: histogram-partition counting sort (u32 payload) ============
__global__ __launch_bounds__(256) void k_part(const int* __restrict__ row,
                                              const int* __restrict__ col,
                                              int* __restrict__ bcur,
                                              unsigned* __restrict__ bedges, int E, int NB) {
  __shared__ int hist[128];
  __shared__ int gbase[128];
  const int t = threadIdx.x;
  const int base = blockIdx.x * 2048 + t * 8;
  int r[8], c[8];
  if (base + 8 <= E) {
    int4 r0 = *(const int4*)&row[base], r1 = *(const int4*)&row[base + 4];
    int4 c0 = *(const int4*)&col[base], c1 = *(const int4*)&col[base + 4];
    r[0] = r0.x; r[1] = r0.y; r[2] = r0.z; r[3] = r0.w;
    r[4] = r1.x; r[5] = r1.y; r[6] = r1.z; r[7] = r1.w;
    c[0] = c0.x; c[1] = c0.y; c[2] = c0.z; c[3] = c0.w;
    c[4] = c1.x; c[5] = c1.y; c[6] = c1.z; c[7] = c1.w;
  } else {
#pragma unroll
    for (int j = 0; j < 8; ++j) {
      bool ok = (base + j) < E;
      r[j] = ok ? row[base + j] : 0;
      c[j] = ok ? col[base + j] : -1;
    }
  }
  if (t < 128) hist[t] = 0;
  __syncthreads();
#pragma unroll
  for (int j = 0; j < 8; ++j)
    if (c[j] >= 0) atomicAdd(&hist[c[j] >> CBSH], 1);
  __syncthreads();
  if (t < NB && hist[t] > 0) gbase[t] = atomicAdd(&bcur[t * 16], hist[t]);
  __syncthreads();
  if (t < 128) hist[t] = 0;  // reuse as local cursor
  __syncthreads();
#pragma unroll
  for (int j = 0; j < 8; ++j) {
    if (c[j] < 0) continue;
    int b = c[j] >> CBSH;
    int lp = atomicAdd(&hist[b], 1);
    int p = gbase[b] + lp;
    if (p < CCAP)
      bedges[(size_t)b * CCAP + p] = ((unsigned)(c[j] & (CBW - 1)) << 17) | (unsigned)r[j];
  }
}

// ============ scan bucket counts ============
__global__ void k_scanb(const int* __restrict__ bcur, int* __restrict__ bstart, int NB) {
  __shared__ int lds[1024];
  int t = threadIdx.x;
  int v = (t < NB) ? min(bcur[t * 16], CCAP) : 0;
  lds[t] = v;
  __syncthreads();
  for (int off = 1; off < 1024; off <<= 1) {
    int x = (t >= off) ? lds[t - off] : 0;
    __syncthreads();
    lds[t] += x;
    __syncthreads();
  }
  if (t < NB) bstart[t] = (t > 0) ? lds[t - 1] : 0;
}

// ============ pass 2: per-bucket LDS histogram -> rowstart, dinv ============
__global__ __launch_bounds__(256) void k_rows(const int* __restrict__ bcur,
                                              const int* __restrict__ bstart,
                                              const unsigned* __restrict__ bedges,
                                              int* __restrict__ rowstart,
                                              float* __restrict__ dinv, int N) {
  __shared__ int hist[CBW];
  __shared__ int tsum[256];
  int b = blockIdx.x, t = threadIdx.x;
  int cnt = min(bcur[b * 16], CCAP);
  int gbs = bstart[b];
  for (int i = t; i < CBW; i += 256) hist[i] = 0;
  __syncthreads();
  const unsigned* be = bedges + (size_t)b * CCAP;
  for (int i = t; i < cnt; i += 256) atomicAdd(&hist[be[i] >> 17], 1);
  __syncthreads();
  int h0 = hist[t * 4], h1 = hist[t * 4 + 1], h2 = hist[t * 4 + 2], h3 = hist[t * 4 + 3];
  int s0 = h0, s1 = s0 + h1, s2 = s1 + h2, s3 = s2 + h3;
  tsum[t] = s3;
  __syncthreads();
  for (int off = 1; off < 256; off <<= 1) {
    int x = (t >= off) ? tsum[t - off] : 0;
    __syncthreads();
    tsum[t] += x;
    __syncthreads();
  }
  int prefix = (t > 0) ? tsum[t - 1] : 0;
  int node0 = (b << CBSH) + t * 4;
  int ends[4] = {s0, s1, s2, s3};
  int hs[4] = {h0, h1, h2, h3};
#pragma unroll
  for (int j = 0; j < 4; ++j) {
    int node = node0 + j;
    if (node < N) {
      rowstart[node + 1] = gbs + prefix + ends[j];
      dinv[node] = rsqrtf((float)hs[j] + 1.0f);
    }
  }
  if (b == 0 && t == 0) rowstart[0] = 0;
}

// ============ pass 3: per-bucket CSR fill, packed u32 {w:15, src:17} ============
__global__ __launch_bounds__(256) void k_fill2(const int* __restrict__ bcur,
                                               const int* __restrict__ bstart,
                                               const unsigned* __restrict__ bedges,
                                               const int* __restrict__ rowstart,
                                               const float* __restrict__ dinv,
                                               unsigned* __restrict__ csr, int N) {
  __shared__ int cur[CBW];
  __shared__ float dv[CBW];
  int b = blockIdx.x, t = threadIdx.x;
  int cnt = min(bcur[b * 16], CCAP);
  for (int i = t; i < CBW; i += 256) {
    int node = (b << CBSH) + i;
    cur[i] = (node < N) ? rowstart[node] : 0;
    dv[i] = (node < N) ? dinv[node] : 0.0f;
  }
  __syncthreads();
  const unsigned* be = bedges + (size_t)b * CCAP;
  for (int i = t; i < cnt; i += 256) {
    unsigned pe = be[i];
    int src = pe & SRCM;
    int lc = pe >> 17;
    int pos = atomicAdd(&cur[lc], 1);
    float w = dinv[src] * dv[lc];
    unsigned wb = (__float_as_uint(w) + 0x8000u) >> 16;  // bf16 round-to-nearest, sign=0
    csr[pos] = (wb << 17) | (unsigned)src;
  }
}

// ============ W fp32 -> fp16 MFMA B-fragment packs (both weights, one dispatch) ============
__device__ __forceinline__ void cvtW_one(const float* W, __half* Wf, int idx) {
  int i = idx & 7, l = (idx >> 3) & 63, cb = (idx >> 9) & 7, kc = idx >> 12;
  int ks = kc * 32 + ((l >> 4) << 3) + i;
  int c = cb * 16 + (l & 15);
  Wf[idx] = __float2half(W[ks * 128 + c]);
}
__global__ __launch_bounds__(256) void k_cvtWs(const float* __restrict__ W1,
                                               const float* __restrict__ W2,
                                               __half* __restrict__ Wf1,
                                               __half* __restrict__ Wf2) {
  int idx = blockIdx.x * 256 + threadIdx.x;
  if (idx < 64 * 128) cvtW_one(W1, Wf1, idx);
  else if (idx < 192 * 128) cvtW_one(W2, Wf2, idx - 64 * 128);
}

// ============ x fp32 -> fp16 ============
__global__ __launch_bounds__(256) void k_cvt_x(const float* __restrict__ X,
                                               __half* __restrict__ Xh, size_t total4) {
  size_t i = (size_t)(blockIdx.x * 256 + threadIdx.x);
  if (i >= total4) return;
  float4 v = *(const float4*)&X[i * 4];
  __half2* dst = (__half2*)&Xh[i * 4];
  dst[0] = __floats2half2_rn(v.x, v.y);
  dst[1] = __floats2half2_rn(v.z, v.w);
}

// ============ gather-aggregate, 1 wave per node (max TLP), fp16 in/out ============
__global__ __launch_bounds__(256) void k_agg64h(const int* __restrict__ rowstart,
                                                const unsigned* __restrict__ csr,
                                                const float* __restrict__ dinv,
                                                const __half* __restrict__ Xh,
                                                __half* __restrict__ O, int N) {
  int wid = (blockIdx.x * 256 + threadIdx.x) >> 6;
  int lane = threadIdx.x & 63;
  if (wid >= N) return;
  int s = rowstart[wid], e = rowstart[wid + 1];
  float dc = dinv[wid];
  float acc = __half2float(Xh[(size_t)wid * 64 + lane]) * dc * dc;  // self loop
#pragma unroll 4
  for (int i = s; i < e; ++i) {
    unsigned p = csr[i];
    acc += __half2float(Xh[(size_t)(p & SRCM) * 64 + lane]) * decw(p);
  }
  O[(size_t)wid * 64 + lane] = __float2half(acc);
}

__global__ __launch_bounds__(256) void k_agg128h(const int* __restrict__ rowstart,
                                                 const unsigned* __restrict__ csr,
                                                 const float* __restrict__ dinv,
                                                 const __half* __restrict__ H,
                                                 __half* __restrict__ O, int N) {
  int wid = (blockIdx.x * 256 + threadIdx.x) >> 6;
  int lane = threadIdx.x & 63;
  if (wid >= N) return;
  int s = rowstart[wid], e = rowstart[wid + 1];
  float dc = dinv[wid];
  const __half2* Hv = (const __half2*)H;
  float2 hs = __half22float2(Hv[(size_t)wid * 64 + lane]);
  float2 acc;
  acc.x = hs.x * dc * dc;
  acc.y = hs.y * dc * dc;
#pragma unroll 4
  for (int i = s; i < e; ++i) {
    unsigned p = csr[i];
    float w = decw(p);
    float2 h = __half22float2(Hv[(size_t)(p & SRCM) * 64 + lane]);
    acc.x += h.x * w;
    acc.y += h.y * w;
  }
  ((__half2*)O)[(size_t)wid * 64 + lane] = __floats2half2_rn(acc.x, acc.y);
}

// ============ MFMA GEMM: Y[N,128] = lrelu(A[N,K]@W + b), fp16 in/out, fp32 acc ============
// block = 4 waves; wave computes 16 rows x 128 cols. No LDS.
template <int KC>  // K/32
__global__ __launch_bounds__(256) void k_gemm_mfma(const __half* __restrict__ A,
                                                   const __half* __restrict__ Wf,
                                                   const float* __restrict__ bias,
                                                   __half* __restrict__ Y, int N) {
  const int t = threadIdx.x;
  const int l = t & 63;
  const int lr = l & 15, lg = l >> 4;
  const int rowbase = blockIdx.x * 64 + (t >> 6) * 16;
  const int K = KC * 32;
  f32x4 acc[8];
#pragma unroll
  for (int cb = 0; cb < 8; ++cb) acc[cb] = (f32x4){0.f, 0.f, 0.f, 0.f};
  int arow = min(rowbase + lr, N - 1);
  const _Float16* Ap = (const _Float16*)A + (size_t)arow * K + lg * 8;
  const _Float16* Wp = (const _Float16*)Wf + (size_t)l * 8;
#pragma unroll
  for (int kc = 0; kc < KC; ++kc) {
    f16x8 a = *(const f16x8*)(Ap + kc * 32);
#pragma unroll
    for (int cb = 0; cb < 8; ++cb) {
      f16x8 b = *(const f16x8*)(Wp + (size_t)((kc * 8 + cb) * 64) * 8);
      acc[cb] = __builtin_amdgcn_mfma_f32_16x16x32_f16(a, b, acc[cb], 0, 0, 0);
    }
  }
#pragma unroll
  for (int cb = 0; cb < 8; ++cb) {
    int c = cb * 16 + lr;
    float bv = bias[c];
#pragma unroll
    for (int v = 0; v < 4; ++v) {
      int gr = rowbase + lg * 4 + v;
      if (gr < N) Y[(size_t)gr * 128 + c] = __float2half(lrelu(acc[cb][v] + bv));
    }
  }
}

// ============ head: pool (binary search boundaries) + MLP, one block per graph ============
__global__ __launch_bounds__(256) void k_head(const __half* __restrict__ H,
                                              const int* __restrict__ batch, int N,
                                              const float* __restrict__ gfeat,
                                              const float* __restrict__ Wg, const float* __restrict__ bg,
                                              const float* __restrict__ Wf, const float* __restrict__ bf,
                                              const float* __restrict__ Wm1, const float* __restrict__ bm1,
                                              const float* __restrict__ Wm2, const float* __restrict__ bm2,
                                              float* __restrict__ out) {
  __shared__ float2 lds[256];
  __shared__ float p[128], a[256], qf[32], red[2];
  __shared__ int se[2];
  int g = blockIdx.x, t = threadIdx.x;
  if (t < 2) {  // lower_bound(batch, g + t)
    int target = g + t;
    int lo = 0, hi = N;
    while (lo < hi) {
      int mid = (lo + hi) >> 1;
      if (batch[mid] < target) lo = mid + 1; else hi = mid;
    }
    se[t] = lo;
  }
  if (t >= 2 && t < 34) qf[t - 2] = gfeat[(size_t)g * 32 + (t - 2)];
  __syncthreads();
  int s = se[0], e = se[1];
  int c2 = t & 63, q = t >> 6;
  const __half2* Hv = (const __half2*)H;
  float2 acc = make_float2(0.f, 0.f);
  for (int i = s + q; i < e; i += 4) {
    float2 h = __half22float2(Hv[(size_t)i * 64 + c2]);
    acc.x += h.x;
    acc.y += h.y;
  }
  lds[t] = acc;
  __syncthreads();
  if (t < 64) {
    float2 x0 = lds[t], x1 = lds[t + 64], x2 = lds[t + 128], x3 = lds[t + 192];
    float inv = 1.0f / fmaxf((float)(e - s), 1.0f);
    p[t * 2]     = (x0.x + x1.x + x2.x + x3.x) * inv;
    p[t * 2 + 1] = (x0.y + x1.y + x2.y + x3.y) * inv;
  }
  __syncthreads();
  if (t < 128) {
    float z1 = bg[t];
    for (int m = 0; m < 128; ++m) z1 += p[m] * Wg[m * 128 + t];
    float z2 = bf[t];
    for (int m = 0; m < 32; ++m) z2 += qf[m] * Wf[m * 128 + t];
    a[t] = lrelu(z1);
    a[128 + t] = lrelu(z2);
  }
  __syncthreads();
  if (t < 128) {
    float z = bm1[t];
    for (int k = 0; k < 256; ++k) z += a[k] * Wm1[k * 128 + t];
    z = lrelu(z);
    float v = z * Wm2[t];
#pragma unroll
    for (int off = 32; off; off >>= 1) v += __shfl_down(v, off);
    if ((t & 63) == 0) red[t >> 6] = v;
  }
  __syncthreads();
  if (t == 0) out[g] = red[0] + red[1] + bm2[0];
}

extern "C" void kernel_launch(void* const* d_in, const int* in_sizes, int n_in,
                              void* d_out, int out_size, void* d_ws, size_t ws_size,
                              hipStream_t stream) {
  const float* x     = (const float*)d_in[0];
  const int*   ei    = (const int*)d_in[1];
  const int*   batch = (const int*)d_in[2];
  const float* gfeat = (const float*)d_in[3];
  const float* W1 = (const float*)d_in[4];
  const float* b1 = (const float*)d_in[5];
  const float* W2 = (const float*)d_in[6];
  const float* b2 = (const float*)d_in[7];
  const float* Wg = (const float*)d_in[8];
  const float* bg = (const float*)d_in[9];
  const float* Wf = (const float*)d_in[10];
  const float* bf = (const float*)d_in[11];
  const float* Wm1 = (const float*)d_in[12];
  const float* bm1 = (const float*)d_in[13];
  const float* Wm2 = (const float*)d_in[14];
  const float* bm2 = (const float*)d_in[15];
  float* out = (float*)d_out;

  const int N = in_sizes[0] / 64;
  const int E = in_sizes[1] / 2;
  const int G = in_sizes[3] / 32;
  const int* row = ei;
  const int* col = ei + E;
  const int NB = (N + CBW - 1) >> CBSH;

  // ---- workspace layout (~97 MB with aliasing) ----
  char* w = (char*)d_ws;
  size_t off = 0;
  auto alloc = [&](size_t bytes) {
    void* p = w + off;
    off = (off + bytes + 255) & ~(size_t)255;
    return p;
  };
  int*      bcur     = (int*)alloc((size_t)NB * 16 * 4);
  int*      bstart   = (int*)alloc((size_t)NB * 4);
  int*      rowstart = (int*)alloc((size_t)(N + 1) * 4);
  float*    dinv     = (float*)alloc((size_t)N * 4);
  __half*   Wf1      = (__half*)alloc((size_t)64 * 128 * 2);
  __half*   Wf2      = (__half*)alloc((size_t)128 * 128 * 2);
  unsigned* csr      = (unsigned*)alloc((size_t)E * 4);
  __half*   xh       = (__half*)alloc((size_t)N * 64 * 2);
  __half*   h1h      = (__half*)alloc((size_t)N * 128 * 2);
  // regionB: bedges (NB*CCAP u32, ~8MB) then A2h (N*128 fp16, 25.6MB).
  //   bedges dead after k_fill2; A2h first written by k_agg128h (after fill2). Safe.
  char*     regionB  = (char*)alloc((size_t)N * 128 * 2);
  unsigned* bedges   = (unsigned*)regionB;
  __half*   A2h      = (__half*)regionB;
  // regionD: A64h (N*64 fp16) then h2h (N*128 fp16, 25.6MB).
  //   A64h dead after gemm1 writes h1h; h2h first written by gemm2. Safe.
  char*     regionD  = (char*)alloc((size_t)N * 128 * 2);
  __half*   A64h     = (__half*)regionD;
  __half*   h2h      = (__half*)regionD;
  (void)ws_size;

  hipMemsetAsync(bcur, 0, (size_t)NB * 16 * 4, stream);

  // CSR build
  k_part<<<(E + 2047) / 2048, 256, 0, stream>>>(row, col, bcur, bedges, E, NB);
  k_scanb<<<1, 1024, 0, stream>>>(bcur, bstart, NB);
  k_rows<<<NB, 256, 0, stream>>>(bcur, bstart, bedges, rowstart, dinv, N);
  k_fill2<<<NB, 256, 0, stream>>>(bcur, bstart, bedges, rowstart, dinv, csr, N);

  // weight packs + x->fp16
  k_cvtWs<<<(192 * 128 + 255) / 256, 256, 0, stream>>>(W1, W2, Wf1, Wf2);
  const size_t total4 = (size_t)N * 16;
  k_cvt_x<<<(int)((total4 + 255) / 256), 256, 0, stream>>>(x, xh, total4);

  const int aggGrid = (N * 64 + 255) / 256;
  const int gemmGrid = (N + 63) / 64;

  // layer 1
  k_agg64h<<<aggGrid, 256, 0, stream>>>(rowstart, csr, dinv, xh, A64h, N);
  k_gemm_mfma<2><<<gemmGrid, 256, 0, stream>>>(A64h, Wf1, b1, h1h, N);

  // layer 2
  k_agg128h<<<aggGrid, 256, 0, stream>>>(rowstart, csr, dinv, h1h, A2h, N);
  k_gemm_mfma<4><<<gemmGrid, 256, 0, stream>>>(A2h, Wf2, b2, h2h, N);

  // pool + MLP head
  k_head<<<G, 256, 0, stream>>>(h2h, batch, N, gfeat, Wg, bg, Wf, bf, Wm1, bm1, Wm2, bm2, out);
}

// Round 11
// 275.584 us; speedup vs baseline: 1.4548x; 1.1011x over previous
//
#include <hip/hip_runtime.h>
#include <hip/hip_fp16.h>

#define CBW  1024
#define CBSH 10
#define CCAP 20480
#define SRCM 0x1FFFF

typedef _Float16 f16x8 __attribute__((ext_vector_type(8)));
typedef float f32x4 __attribute__((ext_vector_type(4)));

__device__ __forceinline__ float lrelu(float v) { return v >= 0.0f ? v : 0.01f * v; }

// ============ pass 1: histogram-partition counting sort, payload {lc:10|src:17} ============
__global__ __launch_bounds__(256) void k_part(const int* __restrict__ row,
                                              const int* __restrict__ col,
                                              int* __restrict__ bcur,
                                              unsigned* __restrict__ bedges, int E, int NB) {
  __shared__ int hist[128];
  __shared__ int gbase[128];
  const int t = threadIdx.x;
  const int base = blockIdx.x * 2048 + t * 8;
  int r[8], c[8];
  if (base + 8 <= E) {
    int4 r0 = *(const int4*)&row[base], r1 = *(const int4*)&row[base + 4];
    int4 c0 = *(const int4*)&col[base], c1 = *(const int4*)&col[base + 4];
    r[0] = r0.x; r[1] = r0.y; r[2] = r0.z; r[3] = r0.w;
    r[4] = r1.x; r[5] = r1.y; r[6] = r1.z; r[7] = r1.w;
    c[0] = c0.x; c[1] = c0.y; c[2] = c0.z; c[3] = c0.w;
    c[4] = c1.x; c[5] = c1.y; c[6] = c1.z; c[7] = c1.w;
  } else {
#pragma unroll
    for (int j = 0; j < 8; ++j) {
      bool ok = (base + j) < E;
      r[j] = ok ? row[base + j] : 0;
      c[j] = ok ? col[base + j] : -1;
    }
  }
  if (t < 128) hist[t] = 0;
  __syncthreads();
#pragma unroll
  for (int j = 0; j < 8; ++j)
    if (c[j] >= 0) atomicAdd(&hist[c[j] >> CBSH], 1);
  __syncthreads();
  if (t < NB && hist[t] > 0) gbase[t] = atomicAdd(&bcur[t * 16], hist[t]);
  __syncthreads();
  if (t < 128) hist[t] = 0;  // reuse as local cursor
  __syncthreads();
#pragma unroll
  for (int j = 0; j < 8; ++j) {
    if (c[j] < 0) continue;
    int b = c[j] >> CBSH;
    int lp = atomicAdd(&hist[b], 1);
    int p = gbase[b] + lp;
    if (p < CCAP)
      bedges[(size_t)b * CCAP + p] = ((unsigned)(c[j] & (CBW - 1)) << 17) | (unsigned)r[j];
  }
}

// ============ fused CSR build: bucket prefix + histogram + scan -> rowstart/dinv + fill ============
// one block per coarse bucket; global bucket-prefix recomputed per block (NB <= 128).
__global__ __launch_bounds__(256) void k_csr(const int* __restrict__ bcur,
                                             const unsigned* __restrict__ bedges,
                                             int* __restrict__ rowstart,
                                             float* __restrict__ dinv,
                                             unsigned* __restrict__ csr, int N, int NB) {
  __shared__ int hist[CBW];
  __shared__ int tsum[256];
  __shared__ int bpre[128];
  int b = blockIdx.x, t = threadIdx.x;
  if (t < 128) bpre[t] = (t < NB) ? min(bcur[t * 16], CCAP) : 0;
  for (int i = t; i < CBW; i += 256) hist[i] = 0;
  __syncthreads();
  for (int off = 1; off < 128; off <<= 1) {
    int x = (t < 128 && t >= off) ? bpre[t - off] : 0;
    __syncthreads();
    if (t < 128) bpre[t] += x;
    __syncthreads();
  }
  const int gbs = (b > 0) ? bpre[b - 1] : 0;
  const int cnt = min(bcur[b * 16], CCAP);
  const unsigned* be = bedges + (size_t)b * CCAP;
  for (int i = t; i < cnt; i += 256) atomicAdd(&hist[be[i] >> 17], 1);
  __syncthreads();
  int h0 = hist[t * 4], h1 = hist[t * 4 + 1], h2 = hist[t * 4 + 2], h3 = hist[t * 4 + 3];
  int s0 = h0, s1 = s0 + h1, s2 = s1 + h2, s3 = s2 + h3;
  tsum[t] = s3;
  __syncthreads();
  for (int off = 1; off < 256; off <<= 1) {
    int x = (t >= off) ? tsum[t - off] : 0;
    __syncthreads();
    tsum[t] += x;
    __syncthreads();
  }
  int prefix = (t > 0) ? tsum[t - 1] : 0;
  int node0 = (b << CBSH) + t * 4;
  int ends[4] = {s0, s1, s2, s3};
  int hs[4] = {h0, h1, h2, h3};
#pragma unroll
  for (int j = 0; j < 4; ++j) {
    int node = node0 + j;
    if (node < N) {
      rowstart[node + 1] = gbs + prefix + ends[j];
      dinv[node] = rsqrtf((float)hs[j] + 1.0f);
    }
  }
  if (b == 0 && t == 0) rowstart[0] = 0;
  __syncthreads();
  // convert hist -> exclusive cursors (in place)
#pragma unroll
  for (int j = 0; j < 4; ++j) hist[t * 4 + j] = gbs + prefix + ends[j] - hs[j];
  __syncthreads();
  for (int i = t; i < cnt; i += 256) {
    unsigned pe = be[i];
    int pos = atomicAdd(&hist[pe >> 17], 1);
    csr[pos] = pe & SRCM;
  }
}

// ============ merged convert: Xs = dinv*x (fp16), plus W1/W2 MFMA B-fragment packs ============
__device__ __forceinline__ void cvtW_one(const float* W, __half* Wf, int idx) {
  int i = idx & 7, l = (idx >> 3) & 63, cb = (idx >> 9) & 7, kc = idx >> 12;
  int ks = kc * 32 + ((l >> 4) << 3) + i;
  int c = cb * 16 + (l & 15);
  Wf[idx] = __float2half(W[ks * 128 + c]);
}
__global__ __launch_bounds__(256) void k_cvt(const float* __restrict__ X,
                                             const float* __restrict__ dinv,
                                             __half* __restrict__ Xs, int nxblk, size_t total4,
                                             const float* __restrict__ W1,
                                             const float* __restrict__ W2,
                                             __half* __restrict__ Wf1,
                                             __half* __restrict__ Wf2) {
  int blk = blockIdx.x;
  if (blk < nxblk) {
    size_t i = (size_t)blk * 256 + threadIdx.x;
    if (i >= total4) return;
    float d = dinv[i >> 4];  // 16 float4s per node (64 feats)
    float4 v = *(const float4*)&X[i * 4];
    __half2* dst = (__half2*)&Xs[i * 4];
    dst[0] = __floats2half2_rn(v.x * d, v.y * d);
    dst[1] = __floats2half2_rn(v.z * d, v.w * d);
  } else {
    int idx = (blk - nxblk) * 256 + threadIdx.x;
    if (idx < 64 * 128) cvtW_one(W1, Wf1, idx);
    else if (idx < 192 * 128) cvtW_one(W2, Wf2, idx - 64 * 128);
  }
}

// ============ pure gather-sum aggregations (weights factored out) ============
__global__ __launch_bounds__(256) void k_agg64s(const int* __restrict__ rowstart,
                                                const unsigned* __restrict__ csr,
                                                const __half* __restrict__ Xs,
                                                __half* __restrict__ O, int N) {
  int wid = (blockIdx.x * 256 + threadIdx.x) >> 6;
  int lane = threadIdx.x & 63;
  if (wid >= N) return;
  int s = rowstart[wid], e = rowstart[wid + 1];
  float acc = __half2float(Xs[(size_t)wid * 64 + lane]);  // self loop
#pragma unroll 4
  for (int i = s; i < e; ++i)
    acc += __half2float(Xs[(size_t)csr[i] * 64 + lane]);
  O[(size_t)wid * 64 + lane] = __float2half(acc);
}

__global__ __launch_bounds__(256) void k_agg128s(const int* __restrict__ rowstart,
                                                 const unsigned* __restrict__ csr,
                                                 const __half* __restrict__ H,
                                                 __half* __restrict__ O, int N) {
  int wid = (blockIdx.x * 256 + threadIdx.x) >> 6;
  int lane = threadIdx.x & 63;
  if (wid >= N) return;
  int s = rowstart[wid], e = rowstart[wid + 1];
  const __half2* Hv = (const __half2*)H;
  float2 acc = __half22float2(Hv[(size_t)wid * 64 + lane]);  // self loop
#pragma unroll 4
  for (int i = s; i < e; ++i) {
    float2 h = __half22float2(Hv[(size_t)csr[i] * 64 + lane]);
    acc.x += h.x;
    acc.y += h.y;
  }
  ((__half2*)O)[(size_t)wid * 64 + lane] = __floats2half2_rn(acc.x, acc.y);
}

// ============ gemm1: h1s = dinv * lrelu(dinv*(S@W1) + b1), fp16 out ============
__global__ __launch_bounds__(256) void k_gemm1(const __half* __restrict__ A,
                                               const __half* __restrict__ Wf,
                                               const float* __restrict__ bias,
                                               const float* __restrict__ dinv,
                                               __half* __restrict__ Y, int N) {
  const int t = threadIdx.x;
  const int l = t & 63;
  const int lr = l & 15, lg = l >> 4;
  const int rowbase = blockIdx.x * 64 + (t >> 6) * 16;
  if (rowbase >= N) return;
  f32x4 acc[8];
#pragma unroll
  for (int cb = 0; cb < 8; ++cb) acc[cb] = (f32x4){0.f, 0.f, 0.f, 0.f};
  int arow = min(rowbase + lr, N - 1);
  const _Float16* Ap = (const _Float16*)A + (size_t)arow * 64 + lg * 8;
  const _Float16* Wp = (const _Float16*)Wf + (size_t)l * 8;
#pragma unroll
  for (int kc = 0; kc < 2; ++kc) {
    f16x8 a = *(const f16x8*)(Ap + kc * 32);
#pragma unroll
    for (int cb = 0; cb < 8; ++cb) {
      f16x8 b = *(const f16x8*)(Wp + (size_t)((kc * 8 + cb) * 64) * 8);
      acc[cb] = __builtin_amdgcn_mfma_f32_16x16x32_f16(a, b, acc[cb], 0, 0, 0);
    }
  }
  float d[4];
#pragma unroll
  for (int v = 0; v < 4; ++v) {
    int gr = rowbase + lg * 4 + v;
    d[v] = (gr < N) ? dinv[gr] : 0.f;
  }
#pragma unroll
  for (int cb = 0; cb < 8; ++cb) {
    int c = cb * 16 + lr;
    float bv = bias[c];
#pragma unroll
    for (int v = 0; v < 4; ++v) {
      int gr = rowbase + lg * 4 + v;
      if (gr < N)
        Y[(size_t)gr * 128 + c] = __float2half(lrelu(acc[cb][v] * d[v] + bv) * d[v]);
    }
  }
}

// ============ gemm2 + pooling: y = lrelu(dinv*(S2@W2) + b2); pooled[g] += y ============
__global__ __launch_bounds__(256) void k_gemm2pool(const __half* __restrict__ A,
                                                   const __half* __restrict__ Wf,
                                                   const float* __restrict__ bias,
                                                   const float* __restrict__ dinv,
                                                   const int* __restrict__ batch,
                                                   float* __restrict__ pooled, int N) {
  const int t = threadIdx.x;
  const int l = t & 63;
  const int lr = l & 15, lg = l >> 4;
  const int rowbase = blockIdx.x * 64 + (t >> 6) * 16;
  if (rowbase >= N) return;
  f32x4 acc[8];
#pragma unroll
  for (int cb = 0; cb < 8; ++cb) acc[cb] = (f32x4){0.f, 0.f, 0.f, 0.f};
  int arow = min(rowbase + lr, N - 1);
  const _Float16* Ap = (const _Float16*)A + (size_t)arow * 128 + lg * 8;
  const _Float16* Wp = (const _Float16*)Wf + (size_t)l * 8;
#pragma unroll
  for (int kc = 0; kc < 4; ++kc) {
    f16x8 a = *(const f16x8*)(Ap + kc * 32);
#pragma unroll
    for (int cb = 0; cb < 8; ++cb) {
      f16x8 b = *(const f16x8*)(Wp + (size_t)((kc * 8 + cb) * 64) * 8);
      acc[cb] = __builtin_amdgcn_mfma_f32_16x16x32_f16(a, b, acc[cb], 0, 0, 0);
    }
  }
  float d[4];
#pragma unroll
  for (int v = 0; v < 4; ++v) {
    int gr = rowbase + lg * 4 + v;
    d[v] = (gr < N) ? dinv[gr] : 0.f;
  }
  int glo = batch[rowbase];
  int ghi = batch[min(rowbase + 15, N - 1)];
  if (glo == ghi) {
    // fast path: wave's 16 rows all in one graph -> cross-row shuffle reduce
#pragma unroll
    for (int cb = 0; cb < 8; ++cb) {
      int c = cb * 16 + lr;
      float bv = bias[c];
      float s = 0.f;
#pragma unroll
      for (int v = 0; v < 4; ++v) {
        int gr = rowbase + lg * 4 + v;
        if (gr < N) s += lrelu(acc[cb][v] * d[v] + bv);
      }
      s += __shfl_xor(s, 16);
      s += __shfl_xor(s, 32);
      if (lg == 0) atomicAdd(&pooled[(size_t)glo * 128 + c], s);
    }
  } else {
    // boundary block: per-row atomics
#pragma unroll
    for (int cb = 0; cb < 8; ++cb) {
      int c = cb * 16 + lr;
      float bv = bias[c];
#pragma unroll
      for (int v = 0; v < 4; ++v) {
        int gr = rowbase + lg * 4 + v;
        if (gr < N)
          atomicAdd(&pooled[(size_t)batch[gr] * 128 + c], lrelu(acc[cb][v] * d[v] + bv));
      }
    }
  }
}

// ============ head: divide by count (binary search) + MLP, one 128-thread block per graph ============
__global__ __launch_bounds__(128) void k_head(const float* __restrict__ pooled,
                                              const int* __restrict__ batch, int N,
                                              const float* __restrict__ gfeat,
                                              const float* __restrict__ Wg, const float* __restrict__ bg,
                                              const float* __restrict__ Wf, const float* __restrict__ bf,
                                              const float* __restrict__ Wm1, const float* __restrict__ bm1,
                                              const float* __restrict__ Wm2, const float* __restrict__ bm2,
                                              float* __restrict__ out) {
  __shared__ float p[128], a[256], qf[32], red[2];
  __shared__ int se[2];
  int g = blockIdx.x, t = threadIdx.x;
  if (t < 2) {  // lower_bound(batch, g + t)
    int target = g + t;
    int lo = 0, hi = N;
    while (lo < hi) {
      int mid = (lo + hi) >> 1;
      if (batch[mid] < target) lo = mid + 1; else hi = mid;
    }
    se[t] = lo;
  }
  if (t >= 2 && t < 34) qf[t - 2] = gfeat[(size_t)g * 32 + (t - 2)];
  __syncthreads();
  float inv = 1.0f / fmaxf((float)(se[1] - se[0]), 1.0f);
  p[t] = pooled[(size_t)g * 128 + t] * inv;
  __syncthreads();
  float z1 = bg[t];
  for (int m = 0; m < 128; ++m) z1 += p[m] * Wg[m * 128 + t];
  float z2 = bf[t];
  for (int m = 0; m < 32; ++m) z2 += qf[m] * Wf[m * 128 + t];
  a[t] = lrelu(z1);
  a[128 + t] = lrelu(z2);
  __syncthreads();
  float z = bm1[t];
  for (int k = 0; k < 256; ++k) z += a[k] * Wm1[k * 128 + t];
  z = lrelu(z);
  float v = z * Wm2[t];
#pragma unroll
  for (int off = 32; off; off >>= 1) v += __shfl_down(v, off);
  if ((t & 63) == 0) red[t >> 6] = v;
  __syncthreads();
  if (t == 0) out[g] = red[0] + red[1] + bm2[0];
}

extern "C" void kernel_launch(void* const* d_in, const int* in_sizes, int n_in,
                              void* d_out, int out_size, void* d_ws, size_t ws_size,
                              hipStream_t stream) {
  const float* x     = (const float*)d_in[0];
  const int*   ei    = (const int*)d_in[1];
  const int*   batch = (const int*)d_in[2];
  const float* gfeat = (const float*)d_in[3];
  const float* W1 = (const float*)d_in[4];
  const float* b1 = (const float*)d_in[5];
  const float* W2 = (const float*)d_in[6];
  const float* b2 = (const float*)d_in[7];
  const float* Wg = (const float*)d_in[8];
  const float* bg = (const float*)d_in[9];
  const float* Wf = (const float*)d_in[10];
  const float* bf = (const float*)d_in[11];
  const float* Wm1 = (const float*)d_in[12];
  const float* bm1 = (const float*)d_in[13];
  const float* Wm2 = (const float*)d_in[14];
  const float* bm2 = (const float*)d_in[15];
  float* out = (float*)d_out;

  const int N = in_sizes[0] / 64;
  const int E = in_sizes[1] / 2;
  const int G = in_sizes[3] / 32;
  const int* row = ei;
  const int* col = ei + E;
  const int NB = (N + CBW - 1) >> CBSH;  // <=128 assumed (N<=131072)

  // ---- workspace layout ----
  char* w = (char*)d_ws;
  size_t off = 0;
  auto alloc = [&](size_t bytes) {
    void* p = w + off;
    off = (off + bytes + 255) & ~(size_t)255;
    return p;
  };
  int*      bcur     = (int*)alloc((size_t)NB * 16 * 4);   // zeroed
  float*    pooled   = (float*)alloc((size_t)G * 128 * 4); // zeroed (adjacent to bcur)
  size_t    zspan    = off;                                // memset span covers bcur+pooled
  int*      rowstart = (int*)alloc((size_t)(N + 1) * 4);
  float*    dinv     = (float*)alloc((size_t)N * 4);
  __half*   Wf1      = (__half*)alloc((size_t)64 * 128 * 2);
  __half*   Wf2      = (__half*)alloc((size_t)128 * 128 * 2);
  unsigned* csr      = (unsigned*)alloc((size_t)E * 4);
  __half*   Xs       = (__half*)alloc((size_t)N * 64 * 2);
  __half*   h1s      = (__half*)alloc((size_t)N * 128 * 2);
  // regionB: bedges (NB*CCAP u32 ~8MB) then S2 (N*128 fp16 25.6MB); bedges dead after k_csr.
  char*     regionB  = (char*)alloc((size_t)N * 128 * 2);
  unsigned* bedges   = (unsigned*)regionB;
  __half*   S2       = (__half*)regionB;
  __half*   S64      = (__half*)alloc((size_t)N * 64 * 2);
  (void)ws_size;

  hipMemsetAsync(bcur, 0, zspan, stream);

  // CSR build (2 dispatches)
  k_part<<<(E + 2047) / 2048, 256, 0, stream>>>(row, col, bcur, bedges, E, NB);
  k_csr<<<NB, 256, 0, stream>>>(bcur, bedges, rowstart, dinv, csr, N, NB);

  // converts (Xs needs dinv) + weight packs, one dispatch
  const size_t total4 = (size_t)N * 16;
  const int nxblk = (int)((total4 + 255) / 256);
  k_cvt<<<nxblk + 96, 256, 0, stream>>>(x, dinv, Xs, nxblk, total4, W1, W2, Wf1, Wf2);

  const int aggGrid = (N * 64 + 255) / 256;
  const int gemmGrid = (N + 63) / 64;

  // layer 1
  k_agg64s<<<aggGrid, 256, 0, stream>>>(rowstart, csr, Xs, S64, N);
  k_gemm1<<<gemmGrid, 256, 0, stream>>>(S64, Wf1, b1, dinv, h1s, N);

  // layer 2 (+ fused pooling)
  k_agg128s<<<aggGrid, 256, 0, stream>>>(rowstart, csr, h1s, S2, N);
  k_gemm2pool<<<gemmGrid, 256, 0, stream>>>(S2, Wf2, b2, dinv, batch, pooled, N);

  // head MLP
  k_head<<<G, 128, 0, stream>>>(pooled, batch, N, gfeat, Wg, bg, Wf, bf, Wm1, bm1, Wm2, bm2, out);
}

// Round 12
// 253.530 us; speedup vs baseline: 1.5813x; 1.0870x over previous
//
#include <hip/hip_runtime.h>
#include <hip/hip_fp16.h>

#define CBW  1024
#define CBSH 10
#define CCAP 20480
#define SRCM 0x1FFFF

typedef _Float16 f16x8 __attribute__((ext_vector_type(8)));
typedef float f32x4 __attribute__((ext_vector_type(4)));
typedef float f32x2 __attribute__((ext_vector_type(2)));

__device__ __forceinline__ float lrelu(float v) { return v >= 0.0f ? v : 0.01f * v; }

// ---------- fp8 e4m3 helpers (HW builtins with portable fallback) ----------
#if __has_builtin(__builtin_amdgcn_cvt_pk_f32_fp8) && __has_builtin(__builtin_amdgcn_cvt_pk_fp8_f32)
#define FP8_HW 1
#else
#define FP8_HW 0
#endif

#if !FP8_HW
__device__ __forceinline__ float dec1(unsigned b) {
  unsigned s = b & 0x80, e = (b >> 3) & 15, m = b & 7;
  float v = e ? __uint_as_float(((e + 120u) << 23) | (m << 20))
              : (float)m * 0.001953125f;  // subnormal: m * 2^-9
  return s ? -v : v;
}
__device__ __forceinline__ unsigned enc1(float v) {
  unsigned h = __half_as_ushort(__float2half_rn(v));
  unsigned s = (h >> 8) & 0x80;
  int e = (h >> 10) & 31;
  unsigned m = h & 1023;
  if (e == 0) return s;
  if (e > 23) return s | 0x7E;  // clamp to 448
  if (e < 9) {                  // e4m3 subnormal
    float a = fabsf(v) * 512.0f;
    unsigned M = (unsigned)(a + 0.5f);
    if (M > 7) return s | 0x08;
    return s | M;
  }
  unsigned m3 = m >> 7, rest = m & 127;
  if (rest > 64 || (rest == 64 && (m3 & 1))) {
    if (++m3 == 8) { m3 = 0; if (++e > 23) return s | 0x7E; }
  }
  return s | ((unsigned)(e - 8) << 3) | m3;
}
#endif

__device__ __forceinline__ void dec4(unsigned q, float& a, float& b, float& c, float& d) {
#if FP8_HW
  f32x2 lo = __builtin_amdgcn_cvt_pk_f32_fp8((int)q, false);
  f32x2 hi = __builtin_amdgcn_cvt_pk_f32_fp8((int)q, true);
  a = lo[0]; b = lo[1]; c = hi[0]; d = hi[1];
#else
  a = dec1(q & 255); b = dec1((q >> 8) & 255);
  c = dec1((q >> 16) & 255); d = dec1(q >> 24);
#endif
}

__device__ __forceinline__ unsigned enc4(float a, float b, float c, float d) {
#if FP8_HW
  int r = __builtin_amdgcn_cvt_pk_fp8_f32(a, b, 0, false);
  r = __builtin_amdgcn_cvt_pk_fp8_f32(c, d, r, true);
  return (unsigned)r;
#else
  return enc1(a) | (enc1(b) << 8) | (enc1(c) << 16) | (enc1(d) << 24);
#endif
}

// ============ pass 1: histogram-partition counting sort, payload {lc:10|src:17} ============
__global__ __launch_bounds__(256) void k_part(const int* __restrict__ row,
                                              const int* __restrict__ col,
                                              int* __restrict__ bcur,
                                              unsigned* __restrict__ bedges, int E, int NB) {
  __shared__ int hist[128];
  __shared__ int gbase[128];
  const int t = threadIdx.x;
  const int base = blockIdx.x * 2048 + t * 8;
  int r[8], c[8];
  if (base + 8 <= E) {
    int4 r0 = *(const int4*)&row[base], r1 = *(const int4*)&row[base + 4];
    int4 c0 = *(const int4*)&col[base], c1 = *(const int4*)&col[base + 4];
    r[0] = r0.x; r[1] = r0.y; r[2] = r0.z; r[3] = r0.w;
    r[4] = r1.x; r[5] = r1.y; r[6] = r1.z; r[7] = r1.w;
    c[0] = c0.x; c[1] = c0.y; c[2] = c0.z; c[3] = c0.w;
    c[4] = c1.x; c[5] = c1.y; c[6] = c1.z; c[7] = c1.w;
  } else {
#pragma unroll
    for (int j = 0; j < 8; ++j) {
      bool ok = (base + j) < E;
      r[j] = ok ? row[base + j] : 0;
      c[j] = ok ? col[base + j] : -1;
    }
  }
  if (t < 128) hist[t] = 0;
  __syncthreads();
#pragma unroll
  for (int j = 0; j < 8; ++j)
    if (c[j] >= 0) atomicAdd(&hist[c[j] >> CBSH], 1);
  __syncthreads();
  if (t < NB && hist[t] > 0) gbase[t] = atomicAdd(&bcur[t * 16], hist[t]);
  __syncthreads();
  if (t < 128) hist[t] = 0;  // reuse as local cursor
  __syncthreads();
#pragma unroll
  for (int j = 0; j < 8; ++j) {
    if (c[j] < 0) continue;
    int b = c[j] >> CBSH;
    int lp = atomicAdd(&hist[b], 1);
    int p = gbase[b] + lp;
    if (p < CCAP)
      bedges[(size_t)b * CCAP + p] = ((unsigned)(c[j] & (CBW - 1)) << 17) | (unsigned)r[j];
  }
}

// ============ fused CSR build ============
__global__ __launch_bounds__(256) void k_csr(const int* __restrict__ bcur,
                                             const unsigned* __restrict__ bedges,
                                             int* __restrict__ rowstart,
                                             float* __restrict__ dinv,
                                             unsigned* __restrict__ csr, int N, int NB) {
  __shared__ int hist[CBW];
  __shared__ int tsum[256];
  __shared__ int bpre[128];
  int b = blockIdx.x, t = threadIdx.x;
  if (t < 128) bpre[t] = (t < NB) ? min(bcur[t * 16], CCAP) : 0;
  for (int i = t; i < CBW; i += 256) hist[i] = 0;
  __syncthreads();
  for (int off = 1; off < 128; off <<= 1) {
    int x = (t < 128 && t >= off) ? bpre[t - off] : 0;
    __syncthreads();
    if (t < 128) bpre[t] += x;
    __syncthreads();
  }
  const int gbs = (b > 0) ? bpre[b - 1] : 0;
  const int cnt = min(bcur[b * 16], CCAP);
  const unsigned* be = bedges + (size_t)b * CCAP;
  for (int i = t; i < cnt; i += 256) atomicAdd(&hist[be[i] >> 17], 1);
  __syncthreads();
  int h0 = hist[t * 4], h1 = hist[t * 4 + 1], h2 = hist[t * 4 + 2], h3 = hist[t * 4 + 3];
  int s0 = h0, s1 = s0 + h1, s2 = s1 + h2, s3 = s2 + h3;
  tsum[t] = s3;
  __syncthreads();
  for (int off = 1; off < 256; off <<= 1) {
    int x = (t >= off) ? tsum[t - off] : 0;
    __syncthreads();
    tsum[t] += x;
    __syncthreads();
  }
  int prefix = (t > 0) ? tsum[t - 1] : 0;
  int node0 = (b << CBSH) + t * 4;
  int ends[4] = {s0, s1, s2, s3};
  int hs[4] = {h0, h1, h2, h3};
#pragma unroll
  for (int j = 0; j < 4; ++j) {
    int node = node0 + j;
    if (node < N) {
      rowstart[node + 1] = gbs + prefix + ends[j];
      dinv[node] = rsqrtf((float)hs[j] + 1.0f);
    }
  }
  if (b == 0 && t == 0) rowstart[0] = 0;
  __syncthreads();
#pragma unroll
  for (int j = 0; j < 4; ++j) hist[t * 4 + j] = gbs + prefix + ends[j] - hs[j];
  __syncthreads();
  for (int i = t; i < cnt; i += 256) {
    unsigned pe = be[i];
    int pos = atomicAdd(&hist[pe >> 17], 1);
    csr[pos] = pe & SRCM;
  }
}

// ============ merged convert: x8 = fp8(dinv*x), plus W1/W2 MFMA B-fragment packs ============
// W2 pack permutes K: h1 fp8 rows are stored position-major (pos = lr*8+cb -> col = cb*16+lr).
__device__ __forceinline__ void cvtW_one(const float* W, __half* Wf, int idx, bool perm) {
  int i = idx & 7, l = (idx >> 3) & 63, cb = (idx >> 9) & 7, kc = idx >> 12;
  int ks = kc * 32 + ((l >> 4) << 3) + i;
  if (perm) ks = (ks & 7) * 16 + (ks >> 3);  // pi(pos) = logical col
  int c = cb * 16 + (l & 15);
  Wf[idx] = __float2half(W[ks * 128 + c]);
}
__global__ __launch_bounds__(256) void k_cvt(const float* __restrict__ X,
                                             const float* __restrict__ dinv,
                                             unsigned* __restrict__ X8, int nxblk, size_t total4,
                                             const float* __restrict__ W1,
                                             const float* __restrict__ W2,
                                             __half* __restrict__ Wf1,
                                             __half* __restrict__ Wf2) {
  int blk = blockIdx.x;
  if (blk < nxblk) {
    size_t i = (size_t)blk * 256 + threadIdx.x;
    if (i >= total4) return;
    float d = dinv[i >> 4];  // 16 quads per node (64 feats)
    float4 v = *(const float4*)&X[i * 4];
    X8[i] = enc4(v.x * d, v.y * d, v.z * d, v.w * d);
  } else {
    int idx = (blk - nxblk) * 256 + threadIdx.x;
    if (idx < 64 * 128) cvtW_one(W1, Wf1, idx, false);
    else if (idx < 192 * 128) cvtW_one(W2, Wf2, idx - 64 * 128, true);
  }
}

// ============ agg64: wave per node, 4 edge-slots x 16 quads, fp8 gather ============
__global__ __launch_bounds__(256) void k_agg64q(const int* __restrict__ rowstart,
                                                const unsigned* __restrict__ csr,
                                                const unsigned* __restrict__ X8,
                                                __half* __restrict__ O, int N) {
  int wid = (blockIdx.x * 256 + threadIdx.x) >> 6;
  int lane = threadIdx.x & 63;
  if (wid >= N) return;
  int qd = lane & 15, slot = lane >> 4;
  int s = rowstart[wid], e = rowstart[wid + 1];
  float ax = 0.f, ay = 0.f, az = 0.f, aw = 0.f;
  if (slot == 0) dec4(X8[(size_t)wid * 16 + qd], ax, ay, az, aw);  // self
#pragma unroll 2
  for (int i = s + slot; i < e; i += 4) {
    unsigned src = csr[i];
    float bx, by, bz, bw;
    dec4(X8[(size_t)src * 16 + qd], bx, by, bz, bw);
    ax += bx; ay += by; az += bz; aw += bw;
  }
  ax += __shfl_xor(ax, 16); ay += __shfl_xor(ay, 16);
  az += __shfl_xor(az, 16); aw += __shfl_xor(aw, 16);
  ax += __shfl_xor(ax, 32); ay += __shfl_xor(ay, 32);
  az += __shfl_xor(az, 32); aw += __shfl_xor(aw, 32);
  if (slot == 0) {
    __half2 h0 = __floats2half2_rn(ax, ay), h1 = __floats2half2_rn(az, aw);
    uint2 st;
    st.x = *(unsigned*)&h0;
    st.y = *(unsigned*)&h1;
    *(uint2*)(O + (size_t)wid * 64 + qd * 4) = st;
  }
}

// ============ agg128: wave per node, 2 edge-slots x 32 quads, fp8 gather (pos-space) ============
__global__ __launch_bounds__(256) void k_agg128q(const int* __restrict__ rowstart,
                                                 const unsigned* __restrict__ csr,
                                                 const unsigned* __restrict__ H8,
                                                 __half* __restrict__ O, int N) {
  int wid = (blockIdx.x * 256 + threadIdx.x) >> 6;
  int lane = threadIdx.x & 63;
  if (wid >= N) return;
  int qd = lane & 31, slot = lane >> 5;
  int s = rowstart[wid], e = rowstart[wid + 1];
  float ax = 0.f, ay = 0.f, az = 0.f, aw = 0.f;
  if (slot == 0) dec4(H8[(size_t)wid * 32 + qd], ax, ay, az, aw);  // self
#pragma unroll 2
  for (int i = s + slot; i < e; i += 2) {
    unsigned src = csr[i];
    float bx, by, bz, bw;
    dec4(H8[(size_t)src * 32 + qd], bx, by, bz, bw);
    ax += bx; ay += by; az += bz; aw += bw;
  }
  ax += __shfl_xor(ax, 32); ay += __shfl_xor(ay, 32);
  az += __shfl_xor(az, 32); aw += __shfl_xor(aw, 32);
  if (slot == 0) {
    __half2 h0 = __floats2half2_rn(ax, ay), h1 = __floats2half2_rn(az, aw);
    uint2 st;
    st.x = *(unsigned*)&h0;
    st.y = *(unsigned*)&h1;
    *(uint2*)(O + (size_t)wid * 128 + qd * 4) = st;
  }
}

// ============ gemm1: h18 = fp8(dinv * lrelu(dinv*(S64@W1) + b1)), pos-major layout ============
__global__ __launch_bounds__(256) void k_gemm1(const __half* __restrict__ A,
                                               const __half* __restrict__ Wf,
                                               const float* __restrict__ bias,
                                               const float* __restrict__ dinv,
                                               unsigned char* __restrict__ H8, int N) {
  const int t = threadIdx.x;
  const int l = t & 63;
  const int lr = l & 15, lg = l >> 4;
  const int rowbase = blockIdx.x * 64 + (t >> 6) * 16;
  if (rowbase >= N) return;
  f32x4 acc[8];
#pragma unroll
  for (int cb = 0; cb < 8; ++cb) acc[cb] = (f32x4){0.f, 0.f, 0.f, 0.f};
  int arow = min(rowbase + lr, N - 1);
  const _Float16* Ap = (const _Float16*)A + (size_t)arow * 64 + lg * 8;
  const _Float16* Wp = (const _Float16*)Wf + (size_t)l * 8;
#pragma unroll
  for (int kc = 0; kc < 2; ++kc) {
    f16x8 a = *(const f16x8*)(Ap + kc * 32);
#pragma unroll
    for (int cb = 0; cb < 8; ++cb) {
      f16x8 b = *(const f16x8*)(Wp + (size_t)((kc * 8 + cb) * 64) * 8);
      acc[cb] = __builtin_amdgcn_mfma_f32_16x16x32_f16(a, b, acc[cb], 0, 0, 0);
    }
  }
#pragma unroll
  for (int v = 0; v < 4; ++v) {
    int gr = rowbase + lg * 4 + v;
    if (gr >= N) continue;
    float d = dinv[gr];
    float y[8];
#pragma unroll
    for (int cb = 0; cb < 8; ++cb)
      y[cb] = lrelu(acc[cb][v] * d + bias[cb * 16 + lr]) * d;
    uint2 st;
    st.x = enc4(y[0], y[1], y[2], y[3]);
    st.y = enc4(y[4], y[5], y[6], y[7]);
    // pos = lr*8 + cb  (logical col = cb*16+lr; W2 pack permutes to match)
    *(uint2*)(H8 + (size_t)gr * 128 + lr * 8) = st;
  }
}

// ============ gemm2 + pooling (A in pos-space; W2 pack permuted) ============
__global__ __launch_bounds__(256) void k_gemm2pool(const __half* __restrict__ A,
                                                   const __half* __restrict__ Wf,
                                                   const float* __restrict__ bias,
                                                   const float* __restrict__ dinv,
                                                   const int* __restrict__ batch,
                                                   float* __restrict__ pooled, int N) {
  const int t = threadIdx.x;
  const int l = t & 63;
  const int lr = l & 15, lg = l >> 4;
  const int rowbase = blockIdx.x * 64 + (t >> 6) * 16;
  if (rowbase >= N) return;
  f32x4 acc[8];
#pragma unroll
  for (int cb = 0; cb < 8; ++cb) acc[cb] = (f32x4){0.f, 0.f, 0.f, 0.f};
  int arow = min(rowbase + lr, N - 1);
  const _Float16* Ap = (const _Float16*)A + (size_t)arow * 128 + lg * 8;
  const _Float16* Wp = (const _Float16*)Wf + (size_t)l * 8;
#pragma unroll
  for (int kc = 0; kc < 4; ++kc) {
    f16x8 a = *(const f16x8*)(Ap + kc * 32);
#pragma unroll
    for (int cb = 0; cb < 8; ++cb) {
      f16x8 b = *(const f16x8*)(Wp + (size_t)((kc * 8 + cb) * 64) * 8);
      acc[cb] = __builtin_amdgcn_mfma_f32_16x16x32_f16(a, b, acc[cb], 0, 0, 0);
    }
  }
  float d[4];
#pragma unroll
  for (int v = 0; v < 4; ++v) {
    int gr = rowbase + lg * 4 + v;
    d[v] = (gr < N) ? dinv[gr] : 0.f;
  }
  int glo = batch[rowbase];
  int ghi = batch[min(rowbase + 15, N - 1)];
  if (glo == ghi) {
#pragma unroll
    for (int cb = 0; cb < 8; ++cb) {
      int c = cb * 16 + lr;
      float bv = bias[c];
      float s = 0.f;
#pragma unroll
      for (int v = 0; v < 4; ++v) {
        int gr = rowbase + lg * 4 + v;
        if (gr < N) s += lrelu(acc[cb][v] * d[v] + bv);
      }
      s += __shfl_xor(s, 16);
      s += __shfl_xor(s, 32);
      if (lg == 0) atomicAdd(&pooled[(size_t)glo * 128 + c], s);
    }
  } else {
#pragma unroll
    for (int cb = 0; cb < 8; ++cb) {
      int c = cb * 16 + lr;
      float bv = bias[c];
#pragma unroll
      for (int v = 0; v < 4; ++v) {
        int gr = rowbase + lg * 4 + v;
        if (gr < N)
          atomicAdd(&pooled[(size_t)batch[gr] * 128 + c], lrelu(acc[cb][v] * d[v] + bv));
      }
    }
  }
}

// ============ head: divide by count + MLP ============
__global__ __launch_bounds__(128) void k_head(const float* __restrict__ pooled,
                                              const int* __restrict__ batch, int N,
                                              const float* __restrict__ gfeat,
                                              const float* __restrict__ Wg, const float* __restrict__ bg,
                                              const float* __restrict__ Wf, const float* __restrict__ bf,
                                              const float* __restrict__ Wm1, const float* __restrict__ bm1,
                                              const float* __restrict__ Wm2, const float* __restrict__ bm2,
                                              float* __restrict__ out) {
  __shared__ float p[128], a[256], qf[32], red[2];
  __shared__ int se[2];
  int g = blockIdx.x, t = threadIdx.x;
  if (t < 2) {
    int target = g + t;
    int lo = 0, hi = N;
    while (lo < hi) {
      int mid = (lo + hi) >> 1;
      if (batch[mid] < target) lo = mid + 1; else hi = mid;
    }
    se[t] = lo;
  }
  if (t >= 2 && t < 34) qf[t - 2] = gfeat[(size_t)g * 32 + (t - 2)];
  __syncthreads();
  float inv = 1.0f / fmaxf((float)(se[1] - se[0]), 1.0f);
  p[t] = pooled[(size_t)g * 128 + t] * inv;
  __syncthreads();
  float z1 = bg[t];
  for (int m = 0; m < 128; ++m) z1 += p[m] * Wg[m * 128 + t];
  float z2 = bf[t];
  for (int m = 0; m < 32; ++m) z2 += qf[m] * Wf[m * 128 + t];
  a[t] = lrelu(z1);
  a[128 + t] = lrelu(z2);
  __syncthreads();
  float z = bm1[t];
  for (int k = 0; k < 256; ++k) z += a[k] * Wm1[k * 128 + t];
  z = lrelu(z);
  float v = z * Wm2[t];
#pragma unroll
  for (int off = 32; off; off >>= 1) v += __shfl_down(v, off);
  if ((t & 63) == 0) red[t >> 6] = v;
  __syncthreads();
  if (t == 0) out[g] = red[0] + red[1] + bm2[0];
}

extern "C" void kernel_launch(void* const* d_in, const int* in_sizes, int n_in,
                              void* d_out, int out_size, void* d_ws, size_t ws_size,
                              hipStream_t stream) {
  const float* x     = (const float*)d_in[0];
  const int*   ei    = (const int*)d_in[1];
  const int*   batch = (const int*)d_in[2];
  const float* gfeat = (const float*)d_in[3];
  const float* W1 = (const float*)d_in[4];
  const float* b1 = (const float*)d_in[5];
  const float* W2 = (const float*)d_in[6];
  const float* b2 = (const float*)d_in[7];
  const float* Wg = (const float*)d_in[8];
  const float* bg = (const float*)d_in[9];
  const float* Wf = (const float*)d_in[10];
  const float* bf = (const float*)d_in[11];
  const float* Wm1 = (const float*)d_in[12];
  const float* bm1 = (const float*)d_in[13];
  const float* Wm2 = (const float*)d_in[14];
  const float* bm2 = (const float*)d_in[15];
  float* out = (float*)d_out;

  const int N = in_sizes[0] / 64;
  const int E = in_sizes[1] / 2;
  const int G = in_sizes[3] / 32;
  const int* row = ei;
  const int* col = ei + E;
  const int NB = (N + CBW - 1) >> CBSH;  // <=128 (N<=131072)

  // ---- workspace layout ----
  char* w = (char*)d_ws;
  size_t off = 0;
  auto alloc = [&](size_t bytes) {
    void* p = w + off;
    off = (off + bytes + 255) & ~(size_t)255;
    return p;
  };
  int*      bcur     = (int*)alloc((size_t)NB * 16 * 4);   // zeroed
  float*    pooled   = (float*)alloc((size_t)G * 128 * 4); // zeroed (adjacent)
  size_t    zspan    = off;
  int*      rowstart = (int*)alloc((size_t)(N + 1) * 4);
  float*    dinv     = (float*)alloc((size_t)N * 4);
  __half*   Wf1      = (__half*)alloc((size_t)64 * 128 * 2);
  __half*   Wf2      = (__half*)alloc((size_t)128 * 128 * 2);
  unsigned* csr      = (unsigned*)alloc((size_t)E * 4);
  unsigned* x8       = (unsigned*)alloc((size_t)N * 64);        // fp8 quads, N*16 u32
  unsigned char* h18 = (unsigned char*)alloc((size_t)N * 128);  // fp8, pos-major
  __half*   S64      = (__half*)alloc((size_t)N * 64 * 2);
  // regionB: bedges (NB*CCAP u32 ~8MB) then S2 (N*128 fp16 25.6MB); bedges dead after k_csr.
  char*     regionB  = (char*)alloc((size_t)N * 128 * 2);
  unsigned* bedges   = (unsigned*)regionB;
  __half*   S2       = (__half*)regionB;
  (void)ws_size;

  hipMemsetAsync(bcur, 0, zspan, stream);

  // CSR build
  k_part<<<(E + 2047) / 2048, 256, 0, stream>>>(row, col, bcur, bedges, E, NB);
  k_csr<<<NB, 256, 0, stream>>>(bcur, bedges, rowstart, dinv, csr, N, NB);

  // converts (x8 needs dinv) + weight packs
  const size_t total4 = (size_t)N * 16;
  const int nxblk = (int)((total4 + 255) / 256);
  k_cvt<<<nxblk + 96, 256, 0, stream>>>(x, dinv, x8, nxblk, total4, W1, W2, Wf1, Wf2);

  const int aggGrid = (N * 64 + 255) / 256;
  const int gemmGrid = (N + 63) / 64;

  // layer 1
  k_agg64q<<<aggGrid, 256, 0, stream>>>(rowstart, csr, x8, S64, N);
  k_gemm1<<<gemmGrid, 256, 0, stream>>>(S64, Wf1, b1, dinv, h18, N);

  // layer 2 (+ fused pooling)
  k_agg128q<<<aggGrid, 256, 0, stream>>>(rowstart, csr, (const unsigned*)h18, S2, N);
  k_gemm2pool<<<gemmGrid, 256, 0, stream>>>(S2, Wf2, b2, dinv, batch, pooled, N);

  // head MLP
  k_head<<<G, 128, 0, stream>>>(pooled, batch, N, gfeat, Wg, bg, Wf, bf, Wm1, bm1, Wm2, bm2, out);
}

// Round 13
// 229.143 us; speedup vs baseline: 1.7496x; 1.1064x over previous
//
#include <hip/hip_runtime.h>
#include <hip/hip_fp16.h>

#define CBW  1024
#define CBSH 10
#define CCAP 20480
#define SRCM 0x1FFFF

typedef _Float16 f16x8 __attribute__((ext_vector_type(8)));
typedef float f32x4 __attribute__((ext_vector_type(4)));
typedef float f32x2 __attribute__((ext_vector_type(2)));

__device__ __forceinline__ float lrelu(float v) { return v >= 0.0f ? v : 0.01f * v; }

// ---------- fp8 e4m3 helpers (HW builtins with portable fallback) ----------
#if __has_builtin(__builtin_amdgcn_cvt_pk_f32_fp8) && __has_builtin(__builtin_amdgcn_cvt_pk_fp8_f32)
#define FP8_HW 1
#else
#define FP8_HW 0
#endif

#if !FP8_HW
__device__ __forceinline__ float dec1(unsigned b) {
  unsigned s = b & 0x80, e = (b >> 3) & 15, m = b & 7;
  float v = e ? __uint_as_float(((e + 120u) << 23) | (m << 20))
              : (float)m * 0.001953125f;
  return s ? -v : v;
}
__device__ __forceinline__ unsigned enc1(float v) {
  unsigned h = __half_as_ushort(__float2half_rn(v));
  unsigned s = (h >> 8) & 0x80;
  int e = (h >> 10) & 31;
  unsigned m = h & 1023;
  if (e == 0) return s;
  if (e > 23) return s | 0x7E;
  if (e < 9) {
    float a = fabsf(v) * 512.0f;
    unsigned M = (unsigned)(a + 0.5f);
    if (M > 7) return s | 0x08;
    return s | M;
  }
  unsigned m3 = m >> 7, rest = m & 127;
  if (rest > 64 || (rest == 64 && (m3 & 1))) {
    if (++m3 == 8) { m3 = 0; if (++e > 23) return s | 0x7E; }
  }
  return s | ((unsigned)(e - 8) << 3) | m3;
}
#endif

__device__ __forceinline__ void dec4(unsigned q, float& a, float& b, float& c, float& d) {
#if FP8_HW
  f32x2 lo = __builtin_amdgcn_cvt_pk_f32_fp8((int)q, false);
  f32x2 hi = __builtin_amdgcn_cvt_pk_f32_fp8((int)q, true);
  a = lo[0]; b = lo[1]; c = hi[0]; d = hi[1];
#else
  a = dec1(q & 255); b = dec1((q >> 8) & 255);
  c = dec1((q >> 16) & 255); d = dec1(q >> 24);
#endif
}

__device__ __forceinline__ unsigned enc4(float a, float b, float c, float d) {
#if FP8_HW
  int r = __builtin_amdgcn_cvt_pk_fp8_f32(a, b, 0, false);
  r = __builtin_amdgcn_cvt_pk_fp8_f32(c, d, r, true);
  return (unsigned)r;
#else
  return enc1(a) | (enc1(b) << 8) | (enc1(c) << 16) | (enc1(d) << 24);
#endif
}

// ============ pass 1: histogram-partition counting sort, payload {lc:10|src:17} ============
__global__ __launch_bounds__(256) void k_part(const int* __restrict__ row,
                                              const int* __restrict__ col,
                                              int* __restrict__ bcur,
                                              unsigned* __restrict__ bedges, int E, int NB) {
  __shared__ int hist[128];
  __shared__ int gbase[128];
  const int t = threadIdx.x;
  const int base = blockIdx.x * 2048 + t * 8;
  int r[8], c[8];
  if (base + 8 <= E) {
    int4 r0 = *(const int4*)&row[base], r1 = *(const int4*)&row[base + 4];
    int4 c0 = *(const int4*)&col[base], c1 = *(const int4*)&col[base + 4];
    r[0] = r0.x; r[1] = r0.y; r[2] = r0.z; r[3] = r0.w;
    r[4] = r1.x; r[5] = r1.y; r[6] = r1.z; r[7] = r1.w;
    c[0] = c0.x; c[1] = c0.y; c[2] = c0.z; c[3] = c0.w;
    c[4] = c1.x; c[5] = c1.y; c[6] = c1.z; c[7] = c1.w;
  } else {
#pragma unroll
    for (int j = 0; j < 8; ++j) {
      bool ok = (base + j) < E;
      r[j] = ok ? row[base + j] : 0;
      c[j] = ok ? col[base + j] : -1;
    }
  }
  if (t < 128) hist[t] = 0;
  __syncthreads();
#pragma unroll
  for (int j = 0; j < 8; ++j)
    if (c[j] >= 0) atomicAdd(&hist[c[j] >> CBSH], 1);
  __syncthreads();
  if (t < NB && hist[t] > 0) gbase[t] = atomicAdd(&bcur[t * 16], hist[t]);
  __syncthreads();
  if (t < 128) hist[t] = 0;
  __syncthreads();
#pragma unroll
  for (int j = 0; j < 8; ++j) {
    if (c[j] < 0) continue;
    int b = c[j] >> CBSH;
    int lp = atomicAdd(&hist[b], 1);
    int p = gbase[b] + lp;
    if (p < CCAP)
      bedges[(size_t)b * CCAP + p] = ((unsigned)(c[j] & (CBW - 1)) << 17) | (unsigned)r[j];
  }
}

// ============ fused CSR build ============
__global__ __launch_bounds__(256) void k_csr(const int* __restrict__ bcur,
                                             const unsigned* __restrict__ bedges,
                                             int* __restrict__ rowstart,
                                             float* __restrict__ dinv,
                                             unsigned* __restrict__ csr, int N, int NB) {
  __shared__ int hist[CBW];
  __shared__ int tsum[256];
  __shared__ int bpre[128];
  int b = blockIdx.x, t = threadIdx.x;
  if (t < 128) bpre[t] = (t < NB) ? min(bcur[t * 16], CCAP) : 0;
  for (int i = t; i < CBW; i += 256) hist[i] = 0;
  __syncthreads();
  for (int off = 1; off < 128; off <<= 1) {
    int x = (t < 128 && t >= off) ? bpre[t - off] : 0;
    __syncthreads();
    if (t < 128) bpre[t] += x;
    __syncthreads();
  }
  const int gbs = (b > 0) ? bpre[b - 1] : 0;
  const int cnt = min(bcur[b * 16], CCAP);
  const unsigned* be = bedges + (size_t)b * CCAP;
  for (int i = t; i < cnt; i += 256) atomicAdd(&hist[be[i] >> 17], 1);
  __syncthreads();
  int h0 = hist[t * 4], h1 = hist[t * 4 + 1], h2 = hist[t * 4 + 2], h3 = hist[t * 4 + 3];
  int s0 = h0, s1 = s0 + h1, s2 = s1 + h2, s3 = s2 + h3;
  tsum[t] = s3;
  __syncthreads();
  for (int off = 1; off < 256; off <<= 1) {
    int x = (t >= off) ? tsum[t - off] : 0;
    __syncthreads();
    tsum[t] += x;
    __syncthreads();
  }
  int prefix = (t > 0) ? tsum[t - 1] : 0;
  int node0 = (b << CBSH) + t * 4;
  int ends[4] = {s0, s1, s2, s3};
  int hs[4] = {h0, h1, h2, h3};
#pragma unroll
  for (int j = 0; j < 4; ++j) {
    int node = node0 + j;
    if (node < N) {
      rowstart[node + 1] = gbs + prefix + ends[j];
      dinv[node] = rsqrtf((float)hs[j] + 1.0f);
    }
  }
  if (b == 0 && t == 0) rowstart[0] = 0;
  __syncthreads();
#pragma unroll
  for (int j = 0; j < 4; ++j) hist[t * 4 + j] = gbs + prefix + ends[j] - hs[j];
  __syncthreads();
  for (int i = t; i < cnt; i += 256) {
    unsigned pe = be[i];
    int pos = atomicAdd(&hist[pe >> 17], 1);
    csr[pos] = pe & SRCM;
  }
}

// ============ merged convert: x8 = fp8(dinv*x), plus W1/W2 MFMA B-fragment packs ============
__device__ __forceinline__ void cvtW_one(const float* W, __half* Wf, int idx, bool perm) {
  int i = idx & 7, l = (idx >> 3) & 63, cb = (idx >> 9) & 7, kc = idx >> 12;
  int ks = kc * 32 + ((l >> 4) << 3) + i;
  if (perm) ks = (ks & 7) * 16 + (ks >> 3);
  int c = cb * 16 + (l & 15);
  Wf[idx] = __float2half(W[ks * 128 + c]);
}
__global__ __launch_bounds__(256) void k_cvt(const float* __restrict__ X,
                                             const float* __restrict__ dinv,
                                             unsigned* __restrict__ X8, int nxblk, size_t total4,
                                             const float* __restrict__ W1,
                                             const float* __restrict__ W2,
                                             __half* __restrict__ Wf1,
                                             __half* __restrict__ Wf2) {
  int blk = blockIdx.x;
  if (blk < nxblk) {
    size_t i = (size_t)blk * 256 + threadIdx.x;
    if (i >= total4) return;
    float d = dinv[i >> 4];
    float4 v = *(const float4*)&X[i * 4];
    X8[i] = enc4(v.x * d, v.y * d, v.z * d, v.w * d);
  } else {
    int idx = (blk - nxblk) * 256 + threadIdx.x;
    if (idx < 64 * 128) cvtW_one(W1, Wf1, idx, false);
    else if (idx < 192 * 128) cvtW_one(W2, Wf2, idx - 64 * 128, true);
  }
}

// ============ agg64: wave per node, 8 edge-slots x 8 lanes x uint2, fp8 gather ============
__global__ __launch_bounds__(256) void k_agg64q(const int* __restrict__ rowstart,
                                                const unsigned* __restrict__ csr,
                                                const uint2* __restrict__ X8v,  // 8 uint2/node
                                                __half* __restrict__ O, int N) {
  int wid = (blockIdx.x * 256 + threadIdx.x) >> 6;
  int lane = threadIdx.x & 63;
  if (wid >= N) return;
  int qd = lane & 7, slot = lane >> 3;
  int s = rowstart[wid], e = rowstart[wid + 1];
  float a0 = 0, a1 = 0, a2 = 0, a3 = 0, a4 = 0, a5 = 0, a6 = 0, a7 = 0;
  if (slot == 0) {
    uint2 q = X8v[(size_t)wid * 8 + qd];
    dec4(q.x, a0, a1, a2, a3);
    dec4(q.y, a4, a5, a6, a7);
  }
#pragma unroll 2
  for (int i = s + slot; i < e; i += 8) {
    unsigned src = csr[i];
    uint2 q = X8v[(size_t)src * 8 + qd];
    float b0, b1, b2, b3, b4, b5, b6, b7;
    dec4(q.x, b0, b1, b2, b3);
    dec4(q.y, b4, b5, b6, b7);
    a0 += b0; a1 += b1; a2 += b2; a3 += b3;
    a4 += b4; a5 += b5; a6 += b6; a7 += b7;
  }
#pragma unroll
  for (int m = 8; m <= 32; m <<= 1) {
    a0 += __shfl_xor(a0, m); a1 += __shfl_xor(a1, m);
    a2 += __shfl_xor(a2, m); a3 += __shfl_xor(a3, m);
    a4 += __shfl_xor(a4, m); a5 += __shfl_xor(a5, m);
    a6 += __shfl_xor(a6, m); a7 += __shfl_xor(a7, m);
  }
  if (slot == 0) {
    __half2 h01 = __floats2half2_rn(a0, a1), h23 = __floats2half2_rn(a2, a3);
    __half2 h45 = __floats2half2_rn(a4, a5), h67 = __floats2half2_rn(a6, a7);
    uint4 st;
    st.x = *(unsigned*)&h01; st.y = *(unsigned*)&h23;
    st.z = *(unsigned*)&h45; st.w = *(unsigned*)&h67;
    *(uint4*)(O + (size_t)wid * 64 + qd * 8) = st;
  }
}

// ============ agg128: wave per node, 4 edge-slots x 16 lanes x uint2, fp8 gather ============
__global__ __launch_bounds__(256) void k_agg128q(const int* __restrict__ rowstart,
                                                 const unsigned* __restrict__ csr,
                                                 const uint2* __restrict__ H8v,  // 16 uint2/node
                                                 __half* __restrict__ O, int N) {
  int wid = (blockIdx.x * 256 + threadIdx.x) >> 6;
  int lane = threadIdx.x & 63;
  if (wid >= N) return;
  int qd = lane & 15, slot = lane >> 4;
  int s = rowstart[wid], e = rowstart[wid + 1];
  float a0 = 0, a1 = 0, a2 = 0, a3 = 0, a4 = 0, a5 = 0, a6 = 0, a7 = 0;
  if (slot == 0) {
    uint2 q = H8v[(size_t)wid * 16 + qd];
    dec4(q.x, a0, a1, a2, a3);
    dec4(q.y, a4, a5, a6, a7);
  }
#pragma unroll 2
  for (int i = s + slot; i < e; i += 4) {
    unsigned src = csr[i];
    uint2 q = H8v[(size_t)src * 16 + qd];
    float b0, b1, b2, b3, b4, b5, b6, b7;
    dec4(q.x, b0, b1, b2, b3);
    dec4(q.y, b4, b5, b6, b7);
    a0 += b0; a1 += b1; a2 += b2; a3 += b3;
    a4 += b4; a5 += b5; a6 += b6; a7 += b7;
  }
#pragma unroll
  for (int m = 16; m <= 32; m <<= 1) {
    a0 += __shfl_xor(a0, m); a1 += __shfl_xor(a1, m);
    a2 += __shfl_xor(a2, m); a3 += __shfl_xor(a3, m);
    a4 += __shfl_xor(a4, m); a5 += __shfl_xor(a5, m);
    a6 += __shfl_xor(a6, m); a7 += __shfl_xor(a7, m);
  }
  if (slot == 0) {
    __half2 h01 = __floats2half2_rn(a0, a1), h23 = __floats2half2_rn(a2, a3);
    __half2 h45 = __floats2half2_rn(a4, a5), h67 = __floats2half2_rn(a6, a7);
    uint4 st;
    st.x = *(unsigned*)&h01; st.y = *(unsigned*)&h23;
    st.z = *(unsigned*)&h45; st.w = *(unsigned*)&h67;
    *(uint4*)(O + (size_t)wid * 128 + qd * 8) = st;
  }
}

// ============ gemm1: h18 = fp8(dinv * lrelu(dinv*(S64@W1) + b1)), pos-major layout ============
__global__ __launch_bounds__(256) void k_gemm1(const __half* __restrict__ A,
                                               const __half* __restrict__ Wf,
                                               const float* __restrict__ bias,
                                               const float* __restrict__ dinv,
                                               unsigned char* __restrict__ H8, int N) {
  const int t = threadIdx.x;
  const int l = t & 63;
  const int lr = l & 15, lg = l >> 4;
  const int rowbase = blockIdx.x * 64 + (t >> 6) * 16;
  if (rowbase >= N) return;
  f32x4 acc[8];
#pragma unroll
  for (int cb = 0; cb < 8; ++cb) acc[cb] = (f32x4){0.f, 0.f, 0.f, 0.f};
  int arow = min(rowbase + lr, N - 1);
  const _Float16* Ap = (const _Float16*)A + (size_t)arow * 64 + lg * 8;
  const _Float16* Wp = (const _Float16*)Wf + (size_t)l * 8;
#pragma unroll
  for (int kc = 0; kc < 2; ++kc) {
    f16x8 a = *(const f16x8*)(Ap + kc * 32);
#pragma unroll
    for (int cb = 0; cb < 8; ++cb) {
      f16x8 b = *(const f16x8*)(Wp + (size_t)((kc * 8 + cb) * 64) * 8);
      acc[cb] = __builtin_amdgcn_mfma_f32_16x16x32_f16(a, b, acc[cb], 0, 0, 0);
    }
  }
#pragma unroll
  for (int v = 0; v < 4; ++v) {
    int gr = rowbase + lg * 4 + v;
    if (gr >= N) continue;
    float d = dinv[gr];
    float y[8];
#pragma unroll
    for (int cb = 0; cb < 8; ++cb)
      y[cb] = lrelu(acc[cb][v] * d + bias[cb * 16 + lr]) * d;
    uint2 st;
    st.x = enc4(y[0], y[1], y[2], y[3]);
    st.y = enc4(y[4], y[5], y[6], y[7]);
    *(uint2*)(H8 + (size_t)gr * 128 + lr * 8) = st;
  }
}

// ============ gemm2 + pooling (A in pos-space; W2 pack permuted) ============
__global__ __launch_bounds__(256) void k_gemm2pool(const __half* __restrict__ A,
                                                   const __half* __restrict__ Wf,
                                                   const float* __restrict__ bias,
                                                   const float* __restrict__ dinv,
                                                   const int* __restrict__ batch,
                                                   float* __restrict__ pooled, int N) {
  const int t = threadIdx.x;
  const int l = t & 63;
  const int lr = l & 15, lg = l >> 4;
  const int rowbase = blockIdx.x * 64 + (t >> 6) * 16;
  if (rowbase >= N) return;
  f32x4 acc[8];
#pragma unroll
  for (int cb = 0; cb < 8; ++cb) acc[cb] = (f32x4){0.f, 0.f, 0.f, 0.f};
  int arow = min(rowbase + lr, N - 1);
  const _Float16* Ap = (const _Float16*)A + (size_t)arow * 128 + lg * 8;
  const _Float16* Wp = (const _Float16*)Wf + (size_t)l * 8;
#pragma unroll
  for (int kc = 0; kc < 4; ++kc) {
    f16x8 a = *(const f16x8*)(Ap + kc * 32);
#pragma unroll
    for (int cb = 0; cb < 8; ++cb) {
      f16x8 b = *(const f16x8*)(Wp + (size_t)((kc * 8 + cb) * 64) * 8);
      acc[cb] = __builtin_amdgcn_mfma_f32_16x16x32_f16(a, b, acc[cb], 0, 0, 0);
    }
  }
  float d[4];
#pragma unroll
  for (int v = 0; v < 4; ++v) {
    int gr = rowbase + lg * 4 + v;
    d[v] = (gr < N) ? dinv[gr] : 0.f;
  }
  int glo = batch[rowbase];
  int ghi = batch[min(rowbase + 15, N - 1)];
  if (glo == ghi) {
#pragma unroll
    for (int cb = 0; cb < 8; ++cb) {
      int c = cb * 16 + lr;
      float bv = bias[c];
      float s = 0.f;
#pragma unroll
      for (int v = 0; v < 4; ++v) {
        int gr = rowbase + lg * 4 + v;
        if (gr < N) s += lrelu(acc[cb][v] * d[v] + bv);
      }
      s += __shfl_xor(s, 16);
      s += __shfl_xor(s, 32);
      if (lg == 0) atomicAdd(&pooled[(size_t)glo * 128 + c], s);
    }
  } else {
#pragma unroll
    for (int cb = 0; cb < 8; ++cb) {
      int c = cb * 16 + lr;
      float bv = bias[c];
#pragma unroll
      for (int v = 0; v < 4; ++v) {
        int gr = rowbase + lg * 4 + v;
        if (gr < N)
          atomicAdd(&pooled[(size_t)batch[gr] * 128 + c], lrelu(acc[cb][v] * d[v] + bv));
      }
    }
  }
}

// ============ head: divide by count + MLP ============
__global__ __launch_bounds__(128) void k_head(const float* __restrict__ pooled,
                                              const int* __restrict__ batch, int N,
                                              const float* __restrict__ gfeat,
                                              const float* __restrict__ Wg, const float* __restrict__ bg,
                                              const float* __restrict__ Wf, const float* __restrict__ bf,
                                              const float* __restrict__ Wm1, const float* __restrict__ bm1,
                                              const float* __restrict__ Wm2, const float* __restrict__ bm2,
                                              float* __restrict__ out) {
  __shared__ float p[128], a[256], qf[32], red[2];
  __shared__ int se[2];
  int g = blockIdx.x, t = threadIdx.x;
  if (t < 2) {
    int target = g + t;
    int lo = 0, hi = N;
    while (lo < hi) {
      int mid = (lo + hi) >> 1;
      if (batch[mid] < target) lo = mid + 1; else hi = mid;
    }
    se[t] = lo;
  }
  if (t >= 2 && t < 34) qf[t - 2] = gfeat[(size_t)g * 32 + (t - 2)];
  __syncthreads();
  float inv = 1.0f / fmaxf((float)(se[1] - se[0]), 1.0f);
  p[t] = pooled[(size_t)g * 128 + t] * inv;
  __syncthreads();
  float z1 = bg[t];
  for (int m = 0; m < 128; ++m) z1 += p[m] * Wg[m * 128 + t];
  float z2 = bf[t];
  for (int m = 0; m < 32; ++m) z2 += qf[m] * Wf[m * 128 + t];
  a[t] = lrelu(z1);
  a[128 + t] = lrelu(z2);
  __syncthreads();
  float z = bm1[t];
  for (int k = 0; k < 256; ++k) z += a[k] * Wm1[k * 128 + t];
  z = lrelu(z);
  float v = z * Wm2[t];
#pragma unroll
  for (int off = 32; off; off >>= 1) v += __shfl_down(v, off);
  if ((t & 63) == 0) red[t >> 6] = v;
  __syncthreads();
  if (t == 0) out[g] = red[0] + red[1] + bm2[0];
}

extern "C" void kernel_launch(void* const* d_in, const int* in_sizes, int n_in,
                              void* d_out, int out_size, void* d_ws, size_t ws_size,
                              hipStream_t stream) {
  const float* x     = (const float*)d_in[0];
  const int*   ei    = (const int*)d_in[1];
  const int*   batch = (const int*)d_in[2];
  const float* gfeat = (const float*)d_in[3];
  const float* W1 = (const float*)d_in[4];
  const float* b1 = (const float*)d_in[5];
  const float* W2 = (const float*)d_in[6];
  const float* b2 = (const float*)d_in[7];
  const float* Wg = (const float*)d_in[8];
  const float* bg = (const float*)d_in[9];
  const float* Wf = (const float*)d_in[10];
  const float* bf = (const float*)d_in[11];
  const float* Wm1 = (const float*)d_in[12];
  const float* bm1 = (const float*)d_in[13];
  const float* Wm2 = (const float*)d_in[14];
  const float* bm2 = (const float*)d_in[15];
  float* out = (float*)d_out;

  const int N = in_sizes[0] / 64;
  const int E = in_sizes[1] / 2;
  const int G = in_sizes[3] / 32;
  const int* row = ei;
  const int* col = ei + E;
  const int NB = (N + CBW - 1) >> CBSH;

  // ---- workspace layout ----
  char* w = (char*)d_ws;
  size_t off = 0;
  auto alloc = [&](size_t bytes) {
    void* p = w + off;
    off = (off + bytes + 255) & ~(size_t)255;
    return p;
  };
  int*      bcur     = (int*)alloc((size_t)NB * 16 * 4);   // zeroed
  float*    pooled   = (float*)alloc((size_t)G * 128 * 4); // zeroed (adjacent)
  size_t    zspan    = off;
  int*      rowstart = (int*)alloc((size_t)(N + 1) * 4);
  float*    dinv     = (float*)alloc((size_t)N * 4);
  __half*   Wf1      = (__half*)alloc((size_t)64 * 128 * 2);
  __half*   Wf2      = (__half*)alloc((size_t)128 * 128 * 2);
  unsigned* csr      = (unsigned*)alloc((size_t)E * 4);
  unsigned* x8       = (unsigned*)alloc((size_t)N * 64);        // fp8, 8 uint2/node
  unsigned char* h18 = (unsigned char*)alloc((size_t)N * 128);  // fp8, pos-major
  __half*   S64      = (__half*)alloc((size_t)N * 64 * 2);
  // regionB: bedges (NB*CCAP u32 ~8MB) then S2 (N*128 fp16 25.6MB); bedges dead after k_csr.
  char*     regionB  = (char*)alloc((size_t)N * 128 * 2);
  unsigned* bedges   = (unsigned*)regionB;
  __half*   S2       = (__half*)regionB;
  (void)ws_size;

  hipMemsetAsync(bcur, 0, zspan, stream);

  // CSR build
  k_part<<<(E + 2047) / 2048, 256, 0, stream>>>(row, col, bcur, bedges, E, NB);
  k_csr<<<NB, 256, 0, stream>>>(bcur, bedges, rowstart, dinv, csr, N, NB);

  // converts (x8 needs dinv) + weight packs
  const size_t total4 = (size_t)N * 16;
  const int nxblk = (int)((total4 + 255) / 256);
  k_cvt<<<nxblk + 96, 256, 0, stream>>>(x, dinv, x8, nxblk, total4, W1, W2, Wf1, Wf2);

  const int aggGrid = (N * 64 + 255) / 256;
  const int gemmGrid = (N + 63) / 64;

  // layer 1
  k_agg64q<<<aggGrid, 256, 0, stream>>>(rowstart, csr, (const uint2*)x8, S64, N);
  k_gemm1<<<gemmGrid, 256, 0, stream>>>(S64, Wf1, b1, dinv, h18, N);

  // layer 2 (+ fused pooling)
  k_agg128q<<<aggGrid, 256, 0, stream>>>(rowstart, csr, (const uint2*)h18, S2, N);
  k_gemm2pool<<<gemmGrid, 256, 0, stream>>>(S2, Wf2, b2, dinv, batch, pooled, N);

  // head MLP
  k_head<<<G, 128, 0, stream>>>(pooled, batch, N, gfeat, Wg, bg, Wf, bf, Wm1, bm1, Wm2, bm2, out);
}